// Round 4
// baseline (141.440 us; speedup 1.0000x reference)
//
#include <hip/hip_runtime.h>

typedef unsigned short u16;
typedef __attribute__((ext_vector_type(8))) short bf16x8;
typedef __attribute__((ext_vector_type(4))) float f32x4;

#define NB 64
#define NT 1024
#define NO 128
#define ND 128

__device__ __forceinline__ u16 f2bf(float f) {
    union { float f; unsigned u; } v; v.f = f;
    unsigned r = v.u + 0x7FFFu + ((v.u >> 16) & 1u);
    return (u16)(r >> 16);
}

// load 8 consecutive fp32 and convert to a bf16x8 MFMA fragment
__device__ __forceinline__ bf16x8 frag_from_f32(const float* p) {
    const float4 a = *reinterpret_cast<const float4*>(p);
    const float4 b = *reinterpret_cast<const float4*>(p + 4);
    bf16x8 r;
    r[0] = (short)f2bf(a.x); r[1] = (short)f2bf(a.y);
    r[2] = (short)f2bf(a.z); r[3] = (short)f2bf(a.w);
    r[4] = (short)f2bf(b.x); r[5] = (short)f2bf(b.y);
    r[6] = (short)f2bf(b.z); r[7] = (short)f2bf(b.w);
    return r;
}

// ---------------------------------------------------------------------------
// attn fp32 [B][T][O] -> attnT bf16 [B][O][T]  (+ optional row-major bf16 copy)
__global__ void k_transpose_attn(const float* __restrict__ attn, u16* __restrict__ attnT,
                                 u16* __restrict__ attnB) {
    __shared__ float tile[32][33];
    int bid = blockIdx.x;
    int ot = bid & 3;            // O/32 = 4
    int tt = (bid >> 2) & 31;    // T/32 = 32
    int b  = bid >> 7;
    int t0 = tt * 32, o0 = ot * 32;
    int tx = threadIdx.x & 31, ty = threadIdx.x >> 5;  // ty 0..7
    const float* src = attn + ((size_t)b * NT + t0) * NO + o0;
    u16* dstB = attnB ? attnB + ((size_t)b * NT + t0) * NO + o0 : (u16*)0;
#pragma unroll
    for (int i = 0; i < 4; i++) {
        int r = ty + i * 8;
        float v = src[(size_t)r * NO + tx];
        tile[r][tx] = v;
        if (attnB) dstB[(size_t)r * NO + tx] = f2bf(v);
    }
    __syncthreads();
    u16* dst = attnT + ((size_t)b * NO + o0) * NT + t0;
#pragma unroll
    for (int i = 0; i < 4; i++) {
        int r = ty + i * 8;
        dst[(size_t)r * NT + tx] = f2bf(tile[tx][r]);
    }
}

// ---------------------------------------------------------------------------
// Transpose+cast the 4 weight matrices: W[k][n] fp32 -> WT[n][k] bf16
__global__ void k_prep_weights(const float* __restrict__ Wmo, const float* __restrict__ Wmt,
                               const float* __restrict__ Wut, const float* __restrict__ Wuo,
                               u16* __restrict__ WmoT, u16* __restrict__ WmtT,
                               u16* __restrict__ WutT, u16* __restrict__ WuoT) {
    int idx = blockIdx.x * 256 + threadIdx.x;
    if (idx < 16384) {
        int k = idx >> 7, n = idx & 127;
        WmoT[n * 128 + k] = f2bf(Wmo[idx]);
    } else if (idx < 32768) {
        int i = idx - 16384; int k = i >> 7, n = i & 127;
        WmtT[n * 128 + k] = f2bf(Wmt[i]);
    } else if (idx < 65536) {
        int i = idx - 32768; int k = i >> 7, n = i & 127;   // Wut is [256][128]
        WutT[n * 256 + k] = f2bf(Wut[i]);
    } else if (idx < 98304) {
        int i = idx - 65536; int k = i >> 7, n = i & 127;
        WuoT[n * 256 + k] = f2bf(Wuo[i]);
    }
}

// ---------------------------------------------------------------------------
// msg_tT[b][n][t] = (tok[b] @ Wmt + bmt)^T   (blocks 0..1023)
// msg_oT[b][n][o] = (obj[b] @ Wmo + bmo)^T   (blocks 1024..1151)
__global__ __launch_bounds__(256, 4)
void k_msg(const float* __restrict__ tok, const float* __restrict__ obj,
           const u16* __restrict__ WmtT, const u16* __restrict__ WmoT,
           const float* __restrict__ bmt, const float* __restrict__ bmo,
           u16* __restrict__ msg_tT, u16* __restrict__ msg_oT) {
    __shared__ u16 lds_m[128][72];   // [n][row_local]
    int bid = blockIdx.x;
    bool is_t = bid < 1024;
    int l = threadIdx.x & 63, w = threadIdx.x >> 6;
    int l15 = l & 15, lk = (l >> 4) * 8, rsub = (l >> 4) * 4;
    const float* X; const u16* WT; const float* bias; int rows_base;
    if (is_t) { X = tok; WT = WmtT; bias = bmt; rows_base = bid * 64; }
    else      { X = obj; WT = WmoT; bias = bmo; rows_base = (bid - 1024) * 64; }
    int wrow = w * 16;
    int row0 = rows_base + wrow;

    f32x4 acc[8] = {};
    const float* xp = X + (size_t)(row0 + l15) * 128;
    bf16x8 acur, anxt, bcur[8], bnxt[8];
    acur = frag_from_f32(xp + lk);
#pragma unroll
    for (int ct = 0; ct < 8; ct++)
        bcur[ct] = *reinterpret_cast<const bf16x8*>(WT + (ct * 16 + l15) * 128 + lk);
#pragma unroll
    for (int kk = 0; kk < 4; kk++) {
        if (kk < 3) {
            int kn = kk * 32 + 32 + lk;
            anxt = frag_from_f32(xp + kn);
#pragma unroll
            for (int ct = 0; ct < 8; ct++)
                bnxt[ct] = *reinterpret_cast<const bf16x8*>(WT + (ct * 16 + l15) * 128 + kn);
        }
#pragma unroll
        for (int ct = 0; ct < 8; ct++)
            acc[ct] = __builtin_amdgcn_mfma_f32_16x16x32_bf16(acur, bcur[ct], acc[ct], 0, 0, 0);
        if (kk < 3) {
            acur = anxt;
#pragma unroll
            for (int ct = 0; ct < 8; ct++) bcur[ct] = bnxt[ct];
        }
    }
#pragma unroll
    for (int ct = 0; ct < 8; ct++) {
        int n = ct * 16 + l15;
        float bv = bias[n];
        ushort4 pk;
        pk.x = f2bf(acc[ct][0] + bv);
        pk.y = f2bf(acc[ct][1] + bv);
        pk.z = f2bf(acc[ct][2] + bv);
        pk.w = f2bf(acc[ct][3] + bv);
        *reinterpret_cast<ushort4*>(&lds_m[n][wrow + rsub]) = pk;
    }
    __syncthreads();
    // coalesced write-out
    int n = threadIdx.x >> 1, h = threadIdx.x & 1;
    const u16* src = &lds_m[n][h * 32];
    u16* dst;
    if (is_t) {
        int b = rows_base >> 10, t0 = rows_base & 1023;
        dst = msg_tT + ((size_t)(b * 128 + n) << 10) + t0 + h * 32;
    } else {
        int b = rows_base >> 7, o0 = rows_base & 127;
        dst = msg_oT + (size_t)(b * 128 + n) * 128 + o0 + h * 32;
    }
#pragma unroll
    for (int i = 0; i < 4; i++)
        *reinterpret_cast<bf16x8*>(dst + i * 8) = *reinterpret_cast<const bf16x8*>(src + i * 8);
}

// ---------------------------------------------------------------------------
// Token side: agg = attn @ msg_o; new_t = LN(tok + relu([tok,agg]@Wut + but))
// Software-pipelined; register-resident LayerNorm.
template<bool USEB>
__global__ __launch_bounds__(256, 4)
void k_token_update(const float* __restrict__ tok, const float* __restrict__ attn,
                    const u16* __restrict__ attnB,
                    const u16* __restrict__ msg_oT, const u16* __restrict__ WutT,
                    const float* __restrict__ bupd, const float* __restrict__ g,
                    const float* __restrict__ beta, float* __restrict__ out) {
    __shared__ u16 agg_lds[64][136];   // [row][128 cols + 8 pad]
    int bid = blockIdx.x;
    int b = bid >> 4;
    int t0 = (bid & 15) * 64;
    int l = threadIdx.x & 63, w = threadIdx.x >> 6;
    int l15 = l & 15, lk = (l >> 4) * 8, rsub = (l >> 4) * 4;
    int wrow = w * 16;

    // Phase A (pipelined): agg = attn @ msg_o, K = 128
    f32x4 acc[8] = {};
    const u16* mo = msg_oT + (size_t)b * 16384;
    const u16*  aB = attnB + ((size_t)(b * NT) + t0 + wrow + l15) * NO;
    const float* aF = attn + ((size_t)(b * NT) + t0 + wrow + l15) * NO;
    bf16x8 acur, anxt, bcur[8], bnxt[8];
    acur = USEB ? *reinterpret_cast<const bf16x8*>(aB + lk) : frag_from_f32(aF + lk);
#pragma unroll
    for (int ct = 0; ct < 8; ct++)
        bcur[ct] = *reinterpret_cast<const bf16x8*>(mo + (ct * 16 + l15) * 128 + lk);
#pragma unroll
    for (int kk = 0; kk < 4; kk++) {
        if (kk < 3) {
            int kn = kk * 32 + 32 + lk;
            anxt = USEB ? *reinterpret_cast<const bf16x8*>(aB + kn) : frag_from_f32(aF + kn);
#pragma unroll
            for (int ct = 0; ct < 8; ct++)
                bnxt[ct] = *reinterpret_cast<const bf16x8*>(mo + (ct * 16 + l15) * 128 + kn);
        }
#pragma unroll
        for (int ct = 0; ct < 8; ct++)
            acc[ct] = __builtin_amdgcn_mfma_f32_16x16x32_bf16(acur, bcur[ct], acc[ct], 0, 0, 0);
        if (kk < 3) {
            acur = anxt;
#pragma unroll
            for (int ct = 0; ct < 8; ct++) bcur[ct] = bnxt[ct];
        }
    }
    // Phase B: acc -> agg_lds in A-fragment layout (wave-local rows)
#pragma unroll
    for (int ct = 0; ct < 8; ct++) {
        int n = ct * 16 + l15;
#pragma unroll
        for (int r = 0; r < 4; r++)
            agg_lds[wrow + rsub + r][n] = f2bf(acc[ct][r]);
    }
    // Phase C (pipelined): MLP, K = 256 (tok rows then agg rows)
    f32x4 accm[8] = {};
    const float* tokp = tok + ((size_t)(b * NT) + t0 + wrow + l15) * ND;
    acur = frag_from_f32(tokp + lk);
#pragma unroll
    for (int ct = 0; ct < 8; ct++)
        bcur[ct] = *reinterpret_cast<const bf16x8*>(WutT + (ct * 16 + l15) * 256 + lk);
#pragma unroll
    for (int kk = 0; kk < 8; kk++) {
        if (kk < 7) {
            int kn = kk * 32 + 32;
            anxt = (kn < 128) ? frag_from_f32(tokp + kn + lk)
                              : *reinterpret_cast<const bf16x8*>(&agg_lds[wrow + l15][kn - 128 + lk]);
#pragma unroll
            for (int ct = 0; ct < 8; ct++)
                bnxt[ct] = *reinterpret_cast<const bf16x8*>(WutT + (ct * 16 + l15) * 256 + kn + lk);
        }
#pragma unroll
        for (int ct = 0; ct < 8; ct++)
            accm[ct] = __builtin_amdgcn_mfma_f32_16x16x32_bf16(acur, bcur[ct], accm[ct], 0, 0, 0);
        if (kk < 7) {
            acur = anxt;
#pragma unroll
            for (int ct = 0; ct < 8; ct++) bcur[ct] = bnxt[ct];
        }
    }
    // Phase D: residual + bias + relu (in regs) + per-row partial sums
    const float* tokr = tok + ((size_t)(b * NT) + t0) * ND;
    float s[4] = {0.f, 0.f, 0.f, 0.f}, sq[4] = {0.f, 0.f, 0.f, 0.f};
#pragma unroll
    for (int ct = 0; ct < 8; ct++) {
        int n = ct * 16 + l15;
        float bv = bupd[n];
#pragma unroll
        for (int r = 0; r < 4; r++) {
            int lr = wrow + rsub + r;
            float v = tokr[(size_t)lr * ND + n] + fmaxf(accm[ct][r] + bv, 0.f);
            accm[ct][r] = v;
            s[r] += v;
            sq[r] += v * v;
        }
    }
    // Phase E: 16-lane reduce, normalize, write
#pragma unroll
    for (int ofs = 1; ofs < 16; ofs <<= 1) {
#pragma unroll
        for (int r = 0; r < 4; r++) {
            s[r]  += __shfl_xor(s[r], ofs, 64);
            sq[r] += __shfl_xor(sq[r], ofs, 64);
        }
    }
    float mu[4], rstd[4];
#pragma unroll
    for (int r = 0; r < 4; r++) {
        mu[r] = s[r] * (1.f / 128.f);
        float var = sq[r] * (1.f / 128.f) - mu[r] * mu[r];
        rstd[r] = rsqrtf(var + 1e-5f);
    }
#pragma unroll
    for (int ct = 0; ct < 8; ct++) {
        int n = ct * 16 + l15;
        float gn = g[n], bn = beta[n];
#pragma unroll
        for (int r = 0; r < 4; r++) {
            int lr = wrow + rsub + r;
            out[((size_t)(b * NT) + t0 + lr) * ND + n] = (accm[ct][r] - mu[r]) * rstd[r] * gn + bn;
        }
    }
}

// ---------------------------------------------------------------------------
// Object side: 512 threads = 8 column-waves (16 cols each), 16 rows/block.
// agg = attn^T @ msg_t (K=1024, pipelined); fused MLP + LN (cross-wave partials).
__global__ __launch_bounds__(512, 4)
void k_obj_update(const float* __restrict__ obj, const u16* __restrict__ attnT,
                  const u16* __restrict__ msg_tT, const u16* __restrict__ WuoT,
                  const float* __restrict__ bupd, const float* __restrict__ g,
                  const float* __restrict__ beta, float* __restrict__ out) {
    __shared__ u16 agg_lds[16][136];
    __shared__ float part_s[16][8], part_sq[16][8];
    int bid = blockIdx.x;
    int b = bid >> 3;
    int o0 = (bid & 7) * 16;
    int l = threadIdx.x & 63, w = threadIdx.x >> 6;   // w 0..7
    int l15 = l & 15, lk = (l >> 4) * 8, rsub = (l >> 4) * 4;
    int ch = w * 16;   // this wave's 16 output columns

    // Phase A: K = 1024, one ct tile per wave, depth-2 pipeline
    f32x4 acc = {};
    const u16* ap = attnT + ((size_t)(b * NO) + o0 + l15) * NT;
    const u16* bp = msg_tT + ((size_t)b << 17) + ((size_t)(ch + l15) << 10);
    bf16x8 acur = *reinterpret_cast<const bf16x8*>(ap + lk);
    bf16x8 bcur = *reinterpret_cast<const bf16x8*>(bp + lk);
#pragma unroll
    for (int kk = 0; kk < 32; kk++) {
        bf16x8 anxt, bnxt;
        if (kk < 31) {
            int kn = kk * 32 + 32 + lk;
            anxt = *reinterpret_cast<const bf16x8*>(ap + kn);
            bnxt = *reinterpret_cast<const bf16x8*>(bp + kn);
        }
        acc = __builtin_amdgcn_mfma_f32_16x16x32_bf16(acur, bcur, acc, 0, 0, 0);
        if (kk < 31) { acur = anxt; bcur = bnxt; }
    }
    // Phase B: acc -> LDS (A layout)
#pragma unroll
    for (int r = 0; r < 4; r++)
        agg_lds[rsub + r][ch + l15] = f2bf(acc[r]);
    __syncthreads();
    // Phase C: MLP (K = 256), this wave's 16 cols
    f32x4 accm = {};
    const float* objp = obj + ((size_t)(b * NO) + o0 + l15) * ND;
    const u16* wp = WuoT + (ch + l15) * 256;
#pragma unroll
    for (int kk = 0; kk < 8; kk++) {
        int k0 = kk * 32;
        bf16x8 a = (k0 < 128) ? frag_from_f32(objp + k0 + lk)
                              : *reinterpret_cast<const bf16x8*>(&agg_lds[l15][k0 - 128 + lk]);
        bf16x8 bfr = *reinterpret_cast<const bf16x8*>(wp + k0 + lk);
        accm = __builtin_amdgcn_mfma_f32_16x16x32_bf16(a, bfr, accm, 0, 0, 0);
    }
    // Phase D: residual + relu + column-partial LN sums
    const float* objr = obj + ((size_t)(b * NO) + o0) * ND;
    int n = ch + l15;
    float bv = bupd[n];
    float s[4], sq[4];
#pragma unroll
    for (int r = 0; r < 4; r++) {
        float v = objr[(size_t)(rsub + r) * ND + n] + fmaxf(accm[r] + bv, 0.f);
        accm[r] = v;
        s[r] = v;
        sq[r] = v * v;
    }
#pragma unroll
    for (int ofs = 1; ofs < 16; ofs <<= 1) {
#pragma unroll
        for (int r = 0; r < 4; r++) {
            s[r]  += __shfl_xor(s[r], ofs, 64);
            sq[r] += __shfl_xor(sq[r], ofs, 64);
        }
    }
    if (l15 < 4) {
        float sv = (l15 == 0) ? s[0] : (l15 == 1) ? s[1] : (l15 == 2) ? s[2] : s[3];
        float qv = (l15 == 0) ? sq[0] : (l15 == 1) ? sq[1] : (l15 == 2) ? sq[2] : sq[3];
        part_s[rsub + l15][w] = sv;
        part_sq[rsub + l15][w] = qv;
    }
    __syncthreads();
    // Phase E: combine 8 partials, normalize, write
#pragma unroll
    for (int r = 0; r < 4; r++) {
        int lr = rsub + r;
        float st = 0.f, qt = 0.f;
#pragma unroll
        for (int ww = 0; ww < 8; ww++) { st += part_s[lr][ww]; qt += part_sq[lr][ww]; }
        float mu = st * (1.f / 128.f);
        float rstd = rsqrtf(qt * (1.f / 128.f) - mu * mu + 1e-5f);
        out[((size_t)(b * NO) + o0 + lr) * ND + n] = (accm[r] - mu) * rstd * g[n] + beta[n];
    }
}

// ---------------------------------------------------------------------------
extern "C" void kernel_launch(void* const* d_in, const int* in_sizes, int n_in,
                              void* d_out, int out_size, void* d_ws, size_t ws_size,
                              hipStream_t stream) {
    const float* tok  = (const float*)d_in[0];
    const float* obj  = (const float*)d_in[1];
    const float* attn = (const float*)d_in[2];
    const float* Wmo  = (const float*)d_in[3];
    const float* bmo  = (const float*)d_in[4];
    const float* Wmt  = (const float*)d_in[5];
    const float* bmt  = (const float*)d_in[6];
    const float* Wut  = (const float*)d_in[7];
    const float* but  = (const float*)d_in[8];
    const float* Wuo  = (const float*)d_in[9];
    const float* buo  = (const float*)d_in[10];
    const float* gt   = (const float*)d_in[11];
    const float* bt   = (const float*)d_in[12];
    const float* go   = (const float*)d_in[13];
    const float* bo   = (const float*)d_in[14];
    float* out = (float*)d_out;

    u16* ws = (u16*)d_ws;
    u16* attnT  = ws;                      // 8388608 u16
    u16* msg_tT = attnT + 8388608;         // 8388608
    u16* msg_oT = msg_tT + 8388608;        // 1048576
    u16* WmoT   = msg_oT + 1048576;        // 16384
    u16* WmtT   = WmoT + 16384;            // 16384
    u16* WutT   = WmtT + 16384;            // 32768
    u16* WuoT   = WutT + 32768;            // 32768
    u16* attnB  = WuoT + 32768;            // 8388608 (optional)
    size_t need_bytes = (size_t)(8388608u * 3 + 1048576u + 16384u * 2 + 32768u * 2) * 2;
    bool hasB = ws_size >= need_bytes;

    k_transpose_attn<<<dim3(8192), dim3(256), 0, stream>>>(attn, attnT, hasB ? attnB : (u16*)0);
    k_prep_weights<<<dim3(384), dim3(256), 0, stream>>>(Wmo, Wmt, Wut, Wuo, WmoT, WmtT, WutT, WuoT);
    k_msg<<<dim3(1152), dim3(256), 0, stream>>>(tok, obj, WmtT, WmoT, bmt, bmo, msg_tT, msg_oT);
    if (hasB)
        k_token_update<true><<<dim3(1024), dim3(256), 0, stream>>>(tok, attn, attnB, msg_oT, WutT, but, gt, bt, out);
    else
        k_token_update<false><<<dim3(1024), dim3(256), 0, stream>>>(tok, attn, attnB, msg_oT, WutT, but, gt, bt, out);
    k_obj_update<<<dim3(512), dim3(512), 0, stream>>>(obj, attnT, msg_tT, WuoT, buo, go, bo,
                                                      out + (size_t)NB * NT * ND);
}

// Round 5
// 125.297 us; speedup vs baseline: 1.1288x; 1.1288x over previous
//
#include <hip/hip_runtime.h>

typedef unsigned short u16;
typedef __attribute__((ext_vector_type(8))) short bf16x8;
typedef __attribute__((ext_vector_type(4))) float f32x4;

#define NB 64
#define NT 1024
#define NO 128
#define ND 128

__device__ __forceinline__ u16 f2bf(float f) {
    union { float f; unsigned u; } v; v.f = f;
    unsigned r = v.u + 0x7FFFu + ((v.u >> 16) & 1u);
    return (u16)(r >> 16);
}
__device__ __forceinline__ float bf2f(short s) {
    union { unsigned u; float f; } v; v.u = ((unsigned)(u16)s) << 16; return v.f;
}

// load 8 consecutive fp32 and convert to a bf16x8 MFMA fragment
__device__ __forceinline__ bf16x8 frag_from_f32(const float* p) {
    const float4 a = *reinterpret_cast<const float4*>(p);
    const float4 b = *reinterpret_cast<const float4*>(p + 4);
    bf16x8 r;
    r[0] = (short)f2bf(a.x); r[1] = (short)f2bf(a.y);
    r[2] = (short)f2bf(a.z); r[3] = (short)f2bf(a.w);
    r[4] = (short)f2bf(b.x); r[5] = (short)f2bf(b.y);
    r[6] = (short)f2bf(b.z); r[7] = (short)f2bf(b.w);
    return r;
}

// ---------------------------------------------------------------------------
// bid<8192: attn fp32 [B][T][O] -> attnT bf16 [B][O][T] (+ optional attnB row-major)
// bid>=8192: tok fp32 [B][T][D] -> tokT bf16 [B][D][T]
__global__ void k_transpose(const float* __restrict__ attn, const float* __restrict__ tok,
                            u16* __restrict__ attnT, u16* __restrict__ attnB,
                            u16* __restrict__ tokT) {
    __shared__ float tile[32][33];
    int bid = blockIdx.x;
    bool isA = bid < 8192;
    int id = isA ? bid : bid - 8192;
    const float* sbase = isA ? attn : tok;
    u16* tbase = isA ? attnT : tokT;
    int ot = id & 3;            // 128/32 = 4
    int tt = (id >> 2) & 31;    // 1024/32 = 32
    int b  = id >> 7;
    int t0 = tt * 32, o0 = ot * 32;
    int tx = threadIdx.x & 31, ty = threadIdx.x >> 5;  // ty 0..7
    const float* src = sbase + ((size_t)b * NT + t0) * 128 + o0;
    u16* dB = (isA && attnB) ? attnB + ((size_t)b * NT + t0) * 128 + o0 : (u16*)0;
#pragma unroll
    for (int i = 0; i < 4; i++) {
        int r = ty + i * 8;
        float v = src[(size_t)r * 128 + tx];
        tile[r][tx] = v;
        if (dB) dB[(size_t)r * 128 + tx] = f2bf(v);
    }
    __syncthreads();
    u16* dst = tbase + ((size_t)b * 128 + o0) * NT + t0;
#pragma unroll
    for (int i = 0; i < 4; i++) {
        int r = ty + i * 8;
        dst[(size_t)r * NT + tx] = f2bf(tile[tx][r]);
    }
}

// ---------------------------------------------------------------------------
// Transpose+cast the 4 weight matrices: W[k][n] fp32 -> WT[n][k] bf16
__global__ void k_prep_weights(const float* __restrict__ Wmo, const float* __restrict__ Wmt,
                               const float* __restrict__ Wut, const float* __restrict__ Wuo,
                               u16* __restrict__ WmoT, u16* __restrict__ WmtT,
                               u16* __restrict__ WutT, u16* __restrict__ WuoT) {
    int idx = blockIdx.x * 256 + threadIdx.x;
    if (idx < 16384) {
        int k = idx >> 7, n = idx & 127;
        WmoT[n * 128 + k] = f2bf(Wmo[idx]);
    } else if (idx < 32768) {
        int i = idx - 16384; int k = i >> 7, n = i & 127;
        WmtT[n * 128 + k] = f2bf(Wmt[i]);
    } else if (idx < 65536) {
        int i = idx - 32768; int k = i >> 7, n = i & 127;   // Wut is [256][128]
        WutT[n * 256 + k] = f2bf(Wut[i]);
    } else if (idx < 98304) {
        int i = idx - 65536; int k = i >> 7, n = i & 127;
        WuoT[n * 256 + k] = f2bf(Wuo[i]);
    }
}

// ---------------------------------------------------------------------------
// msg_oT[b][n][o] = (obj[b] @ Wmo + bmo)^T    grid 128 blocks (64-row tiles)
__global__ __launch_bounds__(256, 4)
void k_msg_o(const float* __restrict__ obj, const u16* __restrict__ WmoT,
             const float* __restrict__ bmo, u16* __restrict__ msg_oT) {
    __shared__ u16 lds_m[128][72];   // [n][row_local]
    int bid = blockIdx.x;
    int rows_base = bid * 64;
    int l = threadIdx.x & 63, w = threadIdx.x >> 6;
    int l15 = l & 15, lk = (l >> 4) * 8, rsub = (l >> 4) * 4;
    int wrow = w * 16;
    int row0 = rows_base + wrow;

    f32x4 acc[8] = {};
    const float* xp = obj + (size_t)(row0 + l15) * 128;
#pragma unroll
    for (int kk = 0; kk < 4; kk++) {
        bf16x8 a = frag_from_f32(xp + kk * 32 + lk);
#pragma unroll
        for (int ct = 0; ct < 8; ct++) {
            bf16x8 bfr = *reinterpret_cast<const bf16x8*>(WmoT + (ct * 16 + l15) * 128 + kk * 32 + lk);
            acc[ct] = __builtin_amdgcn_mfma_f32_16x16x32_bf16(a, bfr, acc[ct], 0, 0, 0);
        }
    }
#pragma unroll
    for (int ct = 0; ct < 8; ct++) {
        int n = ct * 16 + l15;
        float bv = bmo[n];
        ushort4 pk;
        pk.x = f2bf(acc[ct][0] + bv);
        pk.y = f2bf(acc[ct][1] + bv);
        pk.z = f2bf(acc[ct][2] + bv);
        pk.w = f2bf(acc[ct][3] + bv);
        *reinterpret_cast<ushort4*>(&lds_m[n][wrow + rsub]) = pk;
    }
    __syncthreads();
    int n = threadIdx.x >> 1, h = threadIdx.x & 1;
    const u16* src = &lds_m[n][h * 32];
    int b = rows_base >> 7, o0 = rows_base & 127;
    u16* dst = msg_oT + (size_t)(b * 128 + n) * 128 + o0 + h * 32;
#pragma unroll
    for (int i = 0; i < 4; i++)
        *reinterpret_cast<bf16x8*>(dst + i * 8) = *reinterpret_cast<const bf16x8*>(src + i * 8);
}

// ---------------------------------------------------------------------------
// P-slice: P[b][o][d] += over t in slice ks:  attnT[b][o][t] * tokT[b][d][t]
// Also per-slice rowsum of attn over t (for the bmt bias term).
// grid = NB*4 (b,ks), 512 threads = 8 waves; wave w: o rows w*16..+16, all 128 d.
__global__ __launch_bounds__(512, 2)
void k_obj_P(const u16* __restrict__ attnT, const u16* __restrict__ tokT,
             u16* __restrict__ Psl, float* __restrict__ rs_part) {
    int bid = blockIdx.x;
    int b = bid >> 2, ks = bid & 3;
    int l = threadIdx.x & 63, w = threadIdx.x >> 6;   // w 0..7
    int l15 = l & 15, lk = (l >> 4) * 8, rsub = (l >> 4) * 4;
    int kb = ks * 256;
    const u16* ap = attnT + ((size_t)(b * NO) + w * 16 + l15) * NT + kb;
    const u16* bp = tokT  + ((size_t)(b * ND) + l15) * NT + kb;
    f32x4 acc[8] = {};
    float rsum = 0.f;
    bf16x8 acur, anxt, bcur[8], bnxt[8];
    acur = *reinterpret_cast<const bf16x8*>(ap + lk);
#pragma unroll
    for (int ct = 0; ct < 8; ct++)
        bcur[ct] = *reinterpret_cast<const bf16x8*>(bp + (size_t)ct * 16 * NT + lk);
#pragma unroll
    for (int kk = 0; kk < 8; kk++) {
        if (kk < 7) {
            int kn = kk * 32 + 32 + lk;
            anxt = *reinterpret_cast<const bf16x8*>(ap + kn);
#pragma unroll
            for (int ct = 0; ct < 8; ct++)
                bnxt[ct] = *reinterpret_cast<const bf16x8*>(bp + (size_t)ct * 16 * NT + kn);
        }
#pragma unroll
        for (int i = 0; i < 8; i++) rsum += bf2f(acur[i]);
#pragma unroll
        for (int ct = 0; ct < 8; ct++)
            acc[ct] = __builtin_amdgcn_mfma_f32_16x16x32_bf16(acur, bcur[ct], acc[ct], 0, 0, 0);
        if (kk < 7) {
            acur = anxt;
#pragma unroll
            for (int ct = 0; ct < 8; ct++) bcur[ct] = bnxt[ct];
        }
    }
    rsum += __shfl_xor(rsum, 16, 64);
    rsum += __shfl_xor(rsum, 32, 64);
    if (l < 16) rs_part[((size_t)ks * NB + b) * NO + w * 16 + l15] = rsum;
    u16* pout = Psl + (((size_t)(ks * NB + b)) * NO + w * 16) * ND;
#pragma unroll
    for (int ct = 0; ct < 8; ct++)
#pragma unroll
        for (int r = 0; r < 4; r++)
            pout[(size_t)(rsub + r) * ND + ct * 16 + l15] = f2bf(acc[ct][r]);
}

// ---------------------------------------------------------------------------
// Obj finalize: P = sum slices; agg = P@Wmt + rowsum*bmt; new_o = LN(obj + relu([obj,agg]@Wuo + buo))
// grid = NB*4 (b, 32-row o-tile), 256 threads = 4 waves; wave: rows (w&1)*16, cols (w>>1)*64.
__global__ __launch_bounds__(256, 4)
void k_obj_final(const float* __restrict__ obj, const u16* __restrict__ Psl,
                 const float* __restrict__ rs_part, const u16* __restrict__ WmtT,
                 const float* __restrict__ bmt, const u16* __restrict__ WuoT,
                 const float* __restrict__ buo, const float* __restrict__ g,
                 const float* __restrict__ beta, float* __restrict__ out) {
    __shared__ u16 P_lds[32][136];
    __shared__ u16 agg_lds[32][136];
    __shared__ float rs_lds[32];
    __shared__ float part_s[32][2], part_sq[32][2];
    int bid = blockIdx.x;
    int b = bid >> 2, ot = bid & 3;
    int ob = ot * 32;
    int tid = threadIdx.x;
    {   // slice-sum -> P_lds (bf16), rowsum -> rs_lds
        int row = tid >> 3, c0 = (tid & 7) * 16;
        float sm[16];
#pragma unroll
        for (int i = 0; i < 16; i++) sm[i] = 0.f;
#pragma unroll
        for (int ks = 0; ks < 4; ks++) {
            const u16* p = Psl + (((size_t)(ks * NB + b)) * NO + ob + row) * ND + c0;
            bf16x8 v0 = *reinterpret_cast<const bf16x8*>(p);
            bf16x8 v1 = *reinterpret_cast<const bf16x8*>(p + 8);
#pragma unroll
            for (int i = 0; i < 8; i++) { sm[i] += bf2f(v0[i]); sm[8 + i] += bf2f(v1[i]); }
        }
#pragma unroll
        for (int j = 0; j < 4; j++) {
            ushort4 pk;
            pk.x = f2bf(sm[j * 4 + 0]); pk.y = f2bf(sm[j * 4 + 1]);
            pk.z = f2bf(sm[j * 4 + 2]); pk.w = f2bf(sm[j * 4 + 3]);
            *reinterpret_cast<ushort4*>(&P_lds[row][c0 + j * 4]) = pk;
        }
        if (tid < 32) {
            float r = 0.f;
#pragma unroll
            for (int ks = 0; ks < 4; ks++) r += rs_part[((size_t)ks * NB + b) * NO + ob + tid];
            rs_lds[tid] = r;
        }
    }
    __syncthreads();
    int l = tid & 63, w = tid >> 6;
    int l15 = l & 15, lk = (l >> 4) * 8, rsub = (l >> 4) * 4;
    int wr = (w & 1) * 16, wc = (w >> 1) * 64;
    // agg = P @ Wmt (K=128) + rowsum*bmt
    f32x4 agg[4] = {};
#pragma unroll
    for (int kk = 0; kk < 4; kk++) {
        bf16x8 a = *reinterpret_cast<const bf16x8*>(&P_lds[wr + l15][kk * 32 + lk]);
#pragma unroll
        for (int ct = 0; ct < 4; ct++) {
            bf16x8 bf = *reinterpret_cast<const bf16x8*>(WmtT + (wc + ct * 16 + l15) * 128 + kk * 32 + lk);
            agg[ct] = __builtin_amdgcn_mfma_f32_16x16x32_bf16(a, bf, agg[ct], 0, 0, 0);
        }
    }
#pragma unroll
    for (int ct = 0; ct < 4; ct++) {
        int n = wc + ct * 16 + l15;
        float bb = bmt[n];
#pragma unroll
        for (int r = 0; r < 4; r++) {
            float v = agg[ct][r] + rs_lds[wr + rsub + r] * bb;
            agg_lds[wr + rsub + r][n] = f2bf(v);
        }
    }
    __syncthreads();
    // MLP K=256: [obj, agg] @ WuoT
    f32x4 accm[4] = {};
    const float* objp = obj + ((size_t)(b * NO) + ob + wr + l15) * ND;
#pragma unroll
    for (int kk = 0; kk < 8; kk++) {
        int k0 = kk * 32;
        bf16x8 a = (k0 < 128) ? frag_from_f32(objp + k0 + lk)
                              : *reinterpret_cast<const bf16x8*>(&agg_lds[wr + l15][k0 - 128 + lk]);
#pragma unroll
        for (int ct = 0; ct < 4; ct++) {
            bf16x8 bf = *reinterpret_cast<const bf16x8*>(WuoT + (wc + ct * 16 + l15) * 256 + k0 + lk);
            accm[ct] = __builtin_amdgcn_mfma_f32_16x16x32_bf16(a, bf, accm[ct], 0, 0, 0);
        }
    }
    // residual + relu + LN partials (64 cols per wave)
    const float* objr = obj + ((size_t)(b * NO) + ob) * ND;
    float s[4] = {0.f, 0.f, 0.f, 0.f}, sq[4] = {0.f, 0.f, 0.f, 0.f};
#pragma unroll
    for (int ct = 0; ct < 4; ct++) {
        int n = wc + ct * 16 + l15;
        float bv = buo[n];
#pragma unroll
        for (int r = 0; r < 4; r++) {
            int lr = wr + rsub + r;
            float v = objr[(size_t)lr * ND + n] + fmaxf(accm[ct][r] + bv, 0.f);
            accm[ct][r] = v;
            s[r] += v;
            sq[r] += v * v;
        }
    }
#pragma unroll
    for (int ofs = 1; ofs < 16; ofs <<= 1) {
#pragma unroll
        for (int r = 0; r < 4; r++) {
            s[r]  += __shfl_xor(s[r], ofs, 64);
            sq[r] += __shfl_xor(sq[r], ofs, 64);
        }
    }
    if (l15 < 4) {
        float sv = (l15 == 0) ? s[0] : (l15 == 1) ? s[1] : (l15 == 2) ? s[2] : s[3];
        float qv = (l15 == 0) ? sq[0] : (l15 == 1) ? sq[1] : (l15 == 2) ? sq[2] : sq[3];
        part_s[wr + rsub + l15][w >> 1] = sv;
        part_sq[wr + rsub + l15][w >> 1] = qv;
    }
    __syncthreads();
    float mu[4], rstd[4];
#pragma unroll
    for (int r = 0; r < 4; r++) {
        int lr = wr + rsub + r;
        float st = part_s[lr][0] + part_s[lr][1];
        float qt = part_sq[lr][0] + part_sq[lr][1];
        mu[r] = st * (1.f / 128.f);
        rstd[r] = rsqrtf(qt * (1.f / 128.f) - mu[r] * mu[r] + 1e-5f);
    }
#pragma unroll
    for (int ct = 0; ct < 4; ct++) {
        int n = wc + ct * 16 + l15;
        float gn = g[n], bn = beta[n];
#pragma unroll
        for (int r = 0; r < 4; r++) {
            int lr = wr + rsub + r;
            out[((size_t)(b * NO) + ob + lr) * ND + n] = (accm[ct][r] - mu[r]) * rstd[r] * gn + bn;
        }
    }
}

// ---------------------------------------------------------------------------
// Token side: 32-row tiles, grid NB*32 = 2048 blocks, 4 waves;
// wave: rows (w&1)*16, cols (w>>1)*64.
template<bool USEB>
__global__ __launch_bounds__(256, 4)
void k_token_update(const float* __restrict__ tok, const float* __restrict__ attn,
                    const u16* __restrict__ attnB,
                    const u16* __restrict__ msg_oT, const u16* __restrict__ WutT,
                    const float* __restrict__ bupd, const float* __restrict__ g,
                    const float* __restrict__ beta, float* __restrict__ out) {
    __shared__ u16 agg_lds[32][136];
    __shared__ float part_s[32][2], part_sq[32][2];
    int bid = blockIdx.x;
    int b = bid >> 5;
    int t0 = (bid & 31) * 32;
    int l = threadIdx.x & 63, w = threadIdx.x >> 6;
    int l15 = l & 15, lk = (l >> 4) * 8, rsub = (l >> 4) * 4;
    int wr = (w & 1) * 16, wc = (w >> 1) * 64;

    size_t rowg = (size_t)(b * NT) + t0 + wr + l15;
    const u16* mo = msg_oT + (size_t)b * 16384;
    const u16* aB = attnB + rowg * NO;
    const float* aF = attn + rowg * NO;

    // Phase A: agg = attn @ msg_o (K=128), depth-2 pipeline
    f32x4 acc[4] = {};
    bf16x8 acur, anxt, bcur[4], bnxt[4];
    acur = USEB ? *reinterpret_cast<const bf16x8*>(aB + lk) : frag_from_f32(aF + lk);
#pragma unroll
    for (int ct = 0; ct < 4; ct++)
        bcur[ct] = *reinterpret_cast<const bf16x8*>(mo + (wc + ct * 16 + l15) * 128 + lk);
#pragma unroll
    for (int kk = 0; kk < 4; kk++) {
        if (kk < 3) {
            int kn = kk * 32 + 32 + lk;
            anxt = USEB ? *reinterpret_cast<const bf16x8*>(aB + kn) : frag_from_f32(aF + kn);
#pragma unroll
            for (int ct = 0; ct < 4; ct++)
                bnxt[ct] = *reinterpret_cast<const bf16x8*>(mo + (wc + ct * 16 + l15) * 128 + kn);
        }
#pragma unroll
        for (int ct = 0; ct < 4; ct++)
            acc[ct] = __builtin_amdgcn_mfma_f32_16x16x32_bf16(acur, bcur[ct], acc[ct], 0, 0, 0);
        if (kk < 3) {
            acur = anxt;
#pragma unroll
            for (int ct = 0; ct < 4; ct++) bcur[ct] = bnxt[ct];
        }
    }
    // Phase B: acc -> agg_lds (cross-wave col halves -> barrier)
#pragma unroll
    for (int ct = 0; ct < 4; ct++) {
        int n = wc + ct * 16 + l15;
#pragma unroll
        for (int r = 0; r < 4; r++)
            agg_lds[wr + rsub + r][n] = f2bf(acc[ct][r]);
    }
    __syncthreads();
    // Phase C: MLP K=256, depth-2 pipeline
    f32x4 accm[4] = {};
    const float* tokp = tok + rowg * ND;
    acur = frag_from_f32(tokp + lk);
#pragma unroll
    for (int ct = 0; ct < 4; ct++)
        bcur[ct] = *reinterpret_cast<const bf16x8*>(WutT + (wc + ct * 16 + l15) * 256 + lk);
#pragma unroll
    for (int kk = 0; kk < 8; kk++) {
        if (kk < 7) {
            int k0n = kk * 32 + 32;
            anxt = (k0n < 128) ? frag_from_f32(tokp + k0n + lk)
                               : *reinterpret_cast<const bf16x8*>(&agg_lds[wr + l15][k0n - 128 + lk]);
#pragma unroll
            for (int ct = 0; ct < 4; ct++)
                bnxt[ct] = *reinterpret_cast<const bf16x8*>(WutT + (wc + ct * 16 + l15) * 256 + k0n + lk);
        }
#pragma unroll
        for (int ct = 0; ct < 4; ct++)
            accm[ct] = __builtin_amdgcn_mfma_f32_16x16x32_bf16(acur, bcur[ct], accm[ct], 0, 0, 0);
        if (kk < 7) {
            acur = anxt;
#pragma unroll
            for (int ct = 0; ct < 4; ct++) bcur[ct] = bnxt[ct];
        }
    }
    // Phase D: residual + bias + relu + per-row partial sums (64 cols/wave)
    const float* tokr = tok + ((size_t)(b * NT) + t0) * ND;
    float s[4] = {0.f, 0.f, 0.f, 0.f}, sq[4] = {0.f, 0.f, 0.f, 0.f};
#pragma unroll
    for (int ct = 0; ct < 4; ct++) {
        int n = wc + ct * 16 + l15;
        float bv = bupd[n];
#pragma unroll
        for (int r = 0; r < 4; r++) {
            int lr = wr + rsub + r;
            float v = tokr[(size_t)lr * ND + n] + fmaxf(accm[ct][r] + bv, 0.f);
            accm[ct][r] = v;
            s[r] += v;
            sq[r] += v * v;
        }
    }
#pragma unroll
    for (int ofs = 1; ofs < 16; ofs <<= 1) {
#pragma unroll
        for (int r = 0; r < 4; r++) {
            s[r]  += __shfl_xor(s[r], ofs, 64);
            sq[r] += __shfl_xor(sq[r], ofs, 64);
        }
    }
    if (l15 < 4) {
        float sv = (l15 == 0) ? s[0] : (l15 == 1) ? s[1] : (l15 == 2) ? s[2] : s[3];
        float qv = (l15 == 0) ? sq[0] : (l15 == 1) ? sq[1] : (l15 == 2) ? sq[2] : sq[3];
        part_s[wr + rsub + l15][w >> 1] = sv;
        part_sq[wr + rsub + l15][w >> 1] = qv;
    }
    __syncthreads();
    float mu[4], rstd[4];
#pragma unroll
    for (int r = 0; r < 4; r++) {
        int lr = wr + rsub + r;
        float st = part_s[lr][0] + part_s[lr][1];
        float qt = part_sq[lr][0] + part_sq[lr][1];
        mu[r] = st * (1.f / 128.f);
        rstd[r] = rsqrtf(qt * (1.f / 128.f) - mu[r] * mu[r] + 1e-5f);
    }
#pragma unroll
    for (int ct = 0; ct < 4; ct++) {
        int n = wc + ct * 16 + l15;
        float gn = g[n], bn = beta[n];
#pragma unroll
        for (int r = 0; r < 4; r++) {
            int lr = wr + rsub + r;
            out[((size_t)(b * NT) + t0 + lr) * ND + n] = (accm[ct][r] - mu[r]) * rstd[r] * gn + bn;
        }
    }
}

// ---------------------------------------------------------------------------
extern "C" void kernel_launch(void* const* d_in, const int* in_sizes, int n_in,
                              void* d_out, int out_size, void* d_ws, size_t ws_size,
                              hipStream_t stream) {
    const float* tok  = (const float*)d_in[0];
    const float* obj  = (const float*)d_in[1];
    const float* attn = (const float*)d_in[2];
    const float* Wmo  = (const float*)d_in[3];
    const float* bmo  = (const float*)d_in[4];
    const float* Wmt  = (const float*)d_in[5];
    const float* bmt  = (const float*)d_in[6];
    const float* Wut  = (const float*)d_in[7];
    const float* but  = (const float*)d_in[8];
    const float* Wuo  = (const float*)d_in[9];
    const float* buo  = (const float*)d_in[10];
    const float* gt   = (const float*)d_in[11];
    const float* bt   = (const float*)d_in[12];
    const float* go   = (const float*)d_in[13];
    const float* bo   = (const float*)d_in[14];
    float* out = (float*)d_out;

    u16* ws = (u16*)d_ws;
    u16* attnT  = ws;                        // 8388608 u16
    u16* tokT   = attnT + 8388608;           // 8388608
    u16* msg_oT = tokT + 8388608;            // 1048576
    u16* WmoT   = msg_oT + 1048576;          // 16384
    u16* WmtT   = WmoT + 16384;              // 16384
    u16* WutT   = WmtT + 16384;              // 32768
    u16* WuoT   = WutT + 32768;              // 32768
    u16* Psl    = WuoT + 32768;              // 4194304 (bf16 P slices [4][64][128][128])
    float* rs_part = (float*)(Psl + 4194304);// 32768 f32 = 65536 u16
    u16* attnB  = Psl + 4194304 + 65536;     // 8388608 (optional)
    size_t need_noB = (size_t)(8388608u * 2 + 1048576u + 16384u * 2 + 32768u * 2 + 4194304u + 65536u) * 2;
    size_t need_B = need_noB + (size_t)8388608u * 2;
    bool hasB = ws_size >= need_B;

    k_transpose<<<dim3(16384), dim3(256), 0, stream>>>(attn, tok, attnT, hasB ? attnB : (u16*)0, tokT);
    k_prep_weights<<<dim3(384), dim3(256), 0, stream>>>(Wmo, Wmt, Wut, Wuo, WmoT, WmtT, WutT, WuoT);
    k_msg_o<<<dim3(128), dim3(256), 0, stream>>>(obj, WmoT, bmo, msg_oT);
    k_obj_P<<<dim3(256), dim3(512), 0, stream>>>(attnT, tokT, Psl, rs_part);
    if (hasB)
        k_token_update<true><<<dim3(2048), dim3(256), 0, stream>>>(tok, attn, attnB, msg_oT, WutT, but, gt, bt, out);
    else
        k_token_update<false><<<dim3(2048), dim3(256), 0, stream>>>(tok, attn, attnB, msg_oT, WutT, but, gt, bt, out);
    k_obj_final<<<dim3(256), dim3(256), 0, stream>>>(obj, Psl, rs_part, WmtT, bmt, WuoT, buo, go, bo,
                                                     out + (size_t)NB * NT * ND);
}

// Round 6
// 85.626 us; speedup vs baseline: 1.6518x; 1.4633x over previous
//
#include <hip/hip_runtime.h>

typedef unsigned short u16;
typedef __attribute__((ext_vector_type(8))) short bf16x8;
typedef __attribute__((ext_vector_type(4))) float f32x4;

#define NB 64
#define NT 1024
#define NO 128
#define ND 128

__device__ __forceinline__ u16 f2bf(float f) {
    union { float f; unsigned u; } v; v.f = f;
    unsigned r = v.u + 0x7FFFu + ((v.u >> 16) & 1u);
    return (u16)(r >> 16);
}
__device__ __forceinline__ float bf2f(short s) {
    union { unsigned u; float f; } v; v.u = ((unsigned)(u16)s) << 16; return v.f;
}

// load 8 consecutive fp32 and convert to a bf16x8 MFMA fragment
__device__ __forceinline__ bf16x8 frag_from_f32(const float* p) {
    const float4 a = *reinterpret_cast<const float4*>(p);
    const float4 b = *reinterpret_cast<const float4*>(p + 4);
    bf16x8 r;
    r[0] = (short)f2bf(a.x); r[1] = (short)f2bf(a.y);
    r[2] = (short)f2bf(a.z); r[3] = (short)f2bf(a.w);
    r[4] = (short)f2bf(b.x); r[5] = (short)f2bf(b.y);
    r[6] = (short)f2bf(b.z); r[7] = (short)f2bf(b.w);
    return r;
}

// ---------------------------------------------------------------------------
// bid<8192: attn fp32 [B][T][O] -> attnT bf16 [B][O][T] + attnB row-major bf16
// bid>=8192: tok fp32 [B][T][D] -> tokT bf16 [B][D][T]
__global__ void k_transpose(const float* __restrict__ attn, const float* __restrict__ tok,
                            u16* __restrict__ attnT, u16* __restrict__ attnB,
                            u16* __restrict__ tokT) {
    __shared__ float tile[32][33];
    int bid = blockIdx.x;
    bool isA = bid < 8192;
    int id = isA ? bid : bid - 8192;
    const float* sbase = isA ? attn : tok;
    u16* tbase = isA ? attnT : tokT;
    int ot = id & 3;            // 128/32 = 4
    int tt = (id >> 2) & 31;    // 1024/32 = 32
    int b  = id >> 7;
    int t0 = tt * 32, o0 = ot * 32;
    int tx = threadIdx.x & 31, ty = threadIdx.x >> 5;  // ty 0..7
    const float* src = sbase + ((size_t)b * NT + t0) * 128 + o0;
    u16* dB = isA ? attnB + ((size_t)b * NT + t0) * 128 + o0 : (u16*)0;
#pragma unroll
    for (int i = 0; i < 4; i++) {
        int r = ty + i * 8;
        float v = src[(size_t)r * 128 + tx];
        tile[r][tx] = v;
        if (isA) dB[(size_t)r * 128 + tx] = f2bf(v);
    }
    __syncthreads();
    u16* dst = tbase + ((size_t)b * 128 + o0) * NT + t0;
#pragma unroll
    for (int i = 0; i < 4; i++) {
        int r = ty + i * 8;
        dst[(size_t)r * NT + tx] = f2bf(tile[tx][r]);
    }
}

// ---------------------------------------------------------------------------
// Transpose+cast weights: W[k][n] fp32 -> WT[n][k] bf16.
// WutT is stored XOR-SWIZZLED (k ^= (n&7)<<3) for bank-conflict-free ds_read.
__global__ void k_prep_weights(const float* __restrict__ Wmo, const float* __restrict__ Wmt,
                               const float* __restrict__ Wut, const float* __restrict__ Wuo,
                               u16* __restrict__ WmoT, u16* __restrict__ WmtT,
                               u16* __restrict__ WutT, u16* __restrict__ WuoT) {
    int idx = blockIdx.x * 256 + threadIdx.x;
    if (idx < 16384) {
        int k = idx >> 7, n = idx & 127;
        WmoT[n * 128 + k] = f2bf(Wmo[idx]);
    } else if (idx < 32768) {
        int i = idx - 16384; int k = i >> 7, n = i & 127;
        WmtT[n * 128 + k] = f2bf(Wmt[i]);
    } else if (idx < 65536) {
        int i = idx - 32768; int k = i >> 7, n = i & 127;   // Wut is [256][128]
        WutT[n * 256 + (k ^ ((n & 7) << 3))] = f2bf(Wut[i]);   // swizzled
    } else if (idx < 98304) {
        int i = idx - 65536; int k = i >> 7, n = i & 127;
        WuoT[n * 256 + k] = f2bf(Wuo[i]);
    }
}

// ---------------------------------------------------------------------------
// msg_oT[b][n][o] = (obj[b] @ Wmo + bmo)^T, stored XOR-SWIZZLED in o within each n-row.
__global__ __launch_bounds__(256, 4)
void k_msg_o(const float* __restrict__ obj, const u16* __restrict__ WmoT,
             const float* __restrict__ bmo, u16* __restrict__ msg_oT) {
    __shared__ u16 lds_m[128][72];   // [n][row_local]
    int bid = blockIdx.x;
    int rows_base = bid * 64;
    int l = threadIdx.x & 63, w = threadIdx.x >> 6;
    int l15 = l & 15, lk = (l >> 4) * 8, rsub = (l >> 4) * 4;
    int wrow = w * 16;
    int row0 = rows_base + wrow;

    f32x4 acc[8] = {};
    const float* xp = obj + (size_t)(row0 + l15) * 128;
#pragma unroll
    for (int kk = 0; kk < 4; kk++) {
        bf16x8 a = frag_from_f32(xp + kk * 32 + lk);
#pragma unroll
        for (int ct = 0; ct < 8; ct++) {
            bf16x8 bfr = *reinterpret_cast<const bf16x8*>(WmoT + (ct * 16 + l15) * 128 + kk * 32 + lk);
            acc[ct] = __builtin_amdgcn_mfma_f32_16x16x32_bf16(a, bfr, acc[ct], 0, 0, 0);
        }
    }
#pragma unroll
    for (int ct = 0; ct < 8; ct++) {
        int n = ct * 16 + l15;
        float bv = bmo[n];
        ushort4 pk;
        pk.x = f2bf(acc[ct][0] + bv);
        pk.y = f2bf(acc[ct][1] + bv);
        pk.z = f2bf(acc[ct][2] + bv);
        pk.w = f2bf(acc[ct][3] + bv);
        *reinterpret_cast<ushort4*>(&lds_m[n][wrow + rsub]) = pk;
    }
    __syncthreads();
    int n = threadIdx.x >> 1, h = threadIdx.x & 1;
    const u16* src = &lds_m[n][h * 32];
    int b = rows_base >> 7, o0 = rows_base & 127;
    u16* rowp = msg_oT + (size_t)(b * 128 + n) * 128;
#pragma unroll
    for (int i = 0; i < 4; i++) {
        int off = o0 + h * 32 + i * 8;
        *reinterpret_cast<bf16x8*>(rowp + (off ^ ((n & 7) << 3))) =
            *reinterpret_cast<const bf16x8*>(src + i * 8);
    }
}

// ---------------------------------------------------------------------------
// P-slice: P[b][o][d] += over t-slice ks of attn^T[b] @ tok[b]; plus rowsum(attn) partials.
__global__ __launch_bounds__(512, 2)
void k_obj_P(const u16* __restrict__ attnT, const u16* __restrict__ tokT,
             u16* __restrict__ Psl, float* __restrict__ rs_part) {
    int bid = blockIdx.x;
    int b = bid >> 2, ks = bid & 3;
    int l = threadIdx.x & 63, w = threadIdx.x >> 6;   // w 0..7
    int l15 = l & 15, lk = (l >> 4) * 8, rsub = (l >> 4) * 4;
    int kb = ks * 256;
    const u16* ap = attnT + ((size_t)(b * NO) + w * 16 + l15) * NT + kb;
    const u16* bp = tokT  + ((size_t)(b * ND) + l15) * NT + kb;
    f32x4 acc[8] = {};
    float rsum = 0.f;
#pragma unroll
    for (int kk = 0; kk < 8; kk++) {
        bf16x8 a = *reinterpret_cast<const bf16x8*>(ap + kk * 32 + lk);
#pragma unroll
        for (int i = 0; i < 8; i++) rsum += bf2f(a[i]);
#pragma unroll
        for (int ct = 0; ct < 8; ct++) {
            bf16x8 bfr = *reinterpret_cast<const bf16x8*>(bp + (size_t)ct * 16 * NT + kk * 32 + lk);
            acc[ct] = __builtin_amdgcn_mfma_f32_16x16x32_bf16(a, bfr, acc[ct], 0, 0, 0);
        }
    }
    rsum += __shfl_xor(rsum, 16, 64);
    rsum += __shfl_xor(rsum, 32, 64);
    if (l < 16) rs_part[((size_t)ks * NB + b) * NO + w * 16 + l15] = rsum;
    u16* pout = Psl + (((size_t)(ks * NB + b)) * NO + w * 16) * ND;
#pragma unroll
    for (int ct = 0; ct < 8; ct++)
#pragma unroll
        for (int r = 0; r < 4; r++)
            pout[(size_t)(rsub + r) * ND + ct * 16 + l15] = f2bf(acc[ct][r]);
}

// ---------------------------------------------------------------------------
// Obj finalize: P = sum slices; agg = P@Wmt + rowsum*bmt; new_o = LN(obj + relu([obj,agg]@Wuo + buo))
__global__ __launch_bounds__(256, 4)
void k_obj_final(const float* __restrict__ obj, const u16* __restrict__ Psl,
                 const float* __restrict__ rs_part, const u16* __restrict__ WmtT,
                 const float* __restrict__ bmt, const u16* __restrict__ WuoT,
                 const float* __restrict__ buo, const float* __restrict__ g,
                 const float* __restrict__ beta, float* __restrict__ out) {
    __shared__ u16 P_lds[32][136];
    __shared__ u16 agg_lds[32][136];
    __shared__ float rs_lds[32];
    __shared__ float part_s[32][2], part_sq[32][2];
    int bid = blockIdx.x;
    int b = bid >> 2, ot = bid & 3;
    int ob = ot * 32;
    int tid = threadIdx.x;
    {   // slice-sum -> P_lds (bf16), rowsum -> rs_lds
        int row = tid >> 3, c0 = (tid & 7) * 16;
        float sm[16];
#pragma unroll
        for (int i = 0; i < 16; i++) sm[i] = 0.f;
#pragma unroll
        for (int ks = 0; ks < 4; ks++) {
            const u16* p = Psl + (((size_t)(ks * NB + b)) * NO + ob + row) * ND + c0;
            bf16x8 v0 = *reinterpret_cast<const bf16x8*>(p);
            bf16x8 v1 = *reinterpret_cast<const bf16x8*>(p + 8);
#pragma unroll
            for (int i = 0; i < 8; i++) { sm[i] += bf2f(v0[i]); sm[8 + i] += bf2f(v1[i]); }
        }
#pragma unroll
        for (int j = 0; j < 4; j++) {
            ushort4 pk;
            pk.x = f2bf(sm[j * 4 + 0]); pk.y = f2bf(sm[j * 4 + 1]);
            pk.z = f2bf(sm[j * 4 + 2]); pk.w = f2bf(sm[j * 4 + 3]);
            *reinterpret_cast<ushort4*>(&P_lds[row][c0 + j * 4]) = pk;
        }
        if (tid < 32) {
            float r = 0.f;
#pragma unroll
            for (int ks = 0; ks < 4; ks++) r += rs_part[((size_t)ks * NB + b) * NO + ob + tid];
            rs_lds[tid] = r;
        }
    }
    __syncthreads();
    int l = tid & 63, w = tid >> 6;
    int l15 = l & 15, lk = (l >> 4) * 8, rsub = (l >> 4) * 4;
    int wr = (w & 1) * 16, wc = (w >> 1) * 64;
    // agg = P @ Wmt (K=128) + rowsum*bmt
    f32x4 agg[4] = {};
#pragma unroll
    for (int kk = 0; kk < 4; kk++) {
        bf16x8 a = *reinterpret_cast<const bf16x8*>(&P_lds[wr + l15][kk * 32 + lk]);
#pragma unroll
        for (int ct = 0; ct < 4; ct++) {
            bf16x8 bf = *reinterpret_cast<const bf16x8*>(WmtT + (wc + ct * 16 + l15) * 128 + kk * 32 + lk);
            agg[ct] = __builtin_amdgcn_mfma_f32_16x16x32_bf16(a, bf, agg[ct], 0, 0, 0);
        }
    }
#pragma unroll
    for (int ct = 0; ct < 4; ct++) {
        int n = wc + ct * 16 + l15;
        float bb = bmt[n];
#pragma unroll
        for (int r = 0; r < 4; r++) {
            float v = agg[ct][r] + rs_lds[wr + rsub + r] * bb;
            agg_lds[wr + rsub + r][n] = f2bf(v);
        }
    }
    __syncthreads();
    // MLP K=256: [obj, agg] @ WuoT
    f32x4 accm[4] = {};
    const float* objp = obj + ((size_t)(b * NO) + ob + wr + l15) * ND;
#pragma unroll
    for (int kk = 0; kk < 8; kk++) {
        int k0 = kk * 32;
        bf16x8 a = (k0 < 128) ? frag_from_f32(objp + k0 + lk)
                              : *reinterpret_cast<const bf16x8*>(&agg_lds[wr + l15][k0 - 128 + lk]);
#pragma unroll
        for (int ct = 0; ct < 4; ct++) {
            bf16x8 bf = *reinterpret_cast<const bf16x8*>(WuoT + (wc + ct * 16 + l15) * 256 + k0 + lk);
            accm[ct] = __builtin_amdgcn_mfma_f32_16x16x32_bf16(a, bf, accm[ct], 0, 0, 0);
        }
    }
    // residual + relu + LN partials (64 cols per wave)
    const float* objr = obj + ((size_t)(b * NO) + ob) * ND;
    float s[4] = {0.f, 0.f, 0.f, 0.f}, sq[4] = {0.f, 0.f, 0.f, 0.f};
#pragma unroll
    for (int ct = 0; ct < 4; ct++) {
        int n = wc + ct * 16 + l15;
        float bv = buo[n];
#pragma unroll
        for (int r = 0; r < 4; r++) {
            int lr = wr + rsub + r;
            float v = objr[(size_t)lr * ND + n] + fmaxf(accm[ct][r] + bv, 0.f);
            accm[ct][r] = v;
            s[r] += v;
            sq[r] += v * v;
        }
    }
#pragma unroll
    for (int ofs = 1; ofs < 16; ofs <<= 1) {
#pragma unroll
        for (int r = 0; r < 4; r++) {
            s[r]  += __shfl_xor(s[r], ofs, 64);
            sq[r] += __shfl_xor(sq[r], ofs, 64);
        }
    }
    if (l15 < 4) {
        float sv = (l15 == 0) ? s[0] : (l15 == 1) ? s[1] : (l15 == 2) ? s[2] : s[3];
        float qv = (l15 == 0) ? sq[0] : (l15 == 1) ? sq[1] : (l15 == 2) ? sq[2] : sq[3];
        part_s[wr + rsub + l15][w >> 1] = sv;
        part_sq[wr + rsub + l15][w >> 1] = qv;
    }
    __syncthreads();
    float mu[4], rstd[4];
#pragma unroll
    for (int r = 0; r < 4; r++) {
        int lr = wr + rsub + r;
        float st = part_s[lr][0] + part_s[lr][1];
        float qt = part_sq[lr][0] + part_sq[lr][1];
        mu[r] = st * (1.f / 128.f);
        rstd[r] = rsqrtf(qt * (1.f / 128.f) - mu[r] * mu[r] + 1e-5f);
    }
#pragma unroll
    for (int ct = 0; ct < 4; ct++) {
        int n = wc + ct * 16 + l15;
        float gn = g[n], bn = beta[n];
#pragma unroll
        for (int r = 0; r < 4; r++) {
            int lr = wr + rsub + r;
            out[((size_t)(b * NO) + ob + lr) * ND + n] = (accm[ct][r] - mu[r]) * rstd[r] * gn + bn;
        }
    }
}

// ---------------------------------------------------------------------------
// Token side, LDS-panel structure: grid 256 (= 64 b x 4 quarter-batches), 512 thr.
// Stage msg_oT[b] (32KB) + WutT (64KB) into LDS once; each of 8 waves then does
// two independent 16-row x 128-col tiles (no barriers after staging).
__global__ __launch_bounds__(512, 2)
void k_token_update(const float* __restrict__ tok, const u16* __restrict__ attnB,
                    const u16* __restrict__ msg_oT, const u16* __restrict__ WutT,
                    const float* __restrict__ bupd, const float* __restrict__ g,
                    const float* __restrict__ beta, float* __restrict__ out) {
    __shared__ u16 msg_lds[16384];      // 32 KB, swizzled layout
    __shared__ u16 wut_lds[32768];      // 64 KB, swizzled layout
    __shared__ u16 agg_b[8][16][136];   // per-wave agg bounce, 34 KB
    int b = blockIdx.x >> 2, bq = blockIdx.x & 3;
    int tid = threadIdx.x;
    {   // stage panels (linear copy; swizzle already baked into global layout)
        const u16* msrc = msg_oT + (size_t)b * 16384;
#pragma unroll
        for (int i = 0; i < 4; i++) {
            int idx = (i * 512 + tid) * 8;
            *reinterpret_cast<bf16x8*>(&msg_lds[idx]) = *reinterpret_cast<const bf16x8*>(msrc + idx);
        }
#pragma unroll
        for (int i = 0; i < 8; i++) {
            int idx = (i * 512 + tid) * 8;
            *reinterpret_cast<bf16x8*>(&wut_lds[idx]) = *reinterpret_cast<const bf16x8*>(WutT + idx);
        }
    }
    __syncthreads();
    int l = tid & 63, w = tid >> 6;   // 8 waves
    int l15 = l & 15, lk = (l >> 4) * 8, rsub = (l >> 4) * 4;

#pragma unroll
    for (int pass = 0; pass < 2; pass++) {
        int trow = bq * 256 + pass * 128 + w * 16;
        size_t rbase = (size_t)b * NT + trow;

        // Phase A: agg = attn @ msg_o (K=128). A from global attnB, B from LDS.
        const u16* aB = attnB + (rbase + l15) * NO;
        bf16x8 af[4];
#pragma unroll
        for (int kk = 0; kk < 4; kk++)
            af[kk] = *reinterpret_cast<const bf16x8*>(aB + kk * 32 + lk);
        f32x4 acc[8] = {};
#pragma unroll
        for (int kk = 0; kk < 4; kk++) {
#pragma unroll
            for (int ct = 0; ct < 8; ct++) {
                int n = ct * 16 + l15;
                bf16x8 bf = *reinterpret_cast<const bf16x8*>(
                    &msg_lds[n * 128 + ((kk * 32 + lk) ^ ((n & 7) << 3))]);
                acc[ct] = __builtin_amdgcn_mfma_f32_16x16x32_bf16(af[kk], bf, acc[ct], 0, 0, 0);
            }
        }
        // Phase B: acc -> wave-local agg bounce (C layout -> A layout)
#pragma unroll
        for (int ct = 0; ct < 8; ct++) {
            int n = ct * 16 + l15;
#pragma unroll
            for (int r = 0; r < 4; r++)
                agg_b[w][rsub + r][n] = f2bf(acc[ct][r]);
        }
        asm volatile("s_waitcnt lgkmcnt(0)" ::: "memory");
        __builtin_amdgcn_sched_barrier(0);
        // Phase C: MLP K=256. A: tok (global) + agg (LDS); B: wut_lds.
        const float* tokp = tok + (rbase + l15) * ND;
        bf16x8 am[8];
#pragma unroll
        for (int kk = 0; kk < 4; kk++)
            am[kk] = frag_from_f32(tokp + kk * 32 + lk);
#pragma unroll
        for (int kk = 0; kk < 4; kk++)
            am[4 + kk] = *reinterpret_cast<const bf16x8*>(&agg_b[w][l15][kk * 32 + lk]);
        f32x4 accm[8] = {};
#pragma unroll
        for (int kk = 0; kk < 8; kk++) {
#pragma unroll
            for (int ct = 0; ct < 8; ct++) {
                int n = ct * 16 + l15;
                bf16x8 bf = *reinterpret_cast<const bf16x8*>(
                    &wut_lds[n * 256 + ((kk * 32 + lk) ^ ((n & 7) << 3))]);
                accm[ct] = __builtin_amdgcn_mfma_f32_16x16x32_bf16(am[kk], bf, accm[ct], 0, 0, 0);
            }
        }
        // Phase D: residual + bias + relu + per-row partial sums (16 rows, wave-local)
        const float* tokr = tok + rbase * ND;
        float s[4] = {0.f, 0.f, 0.f, 0.f}, sq[4] = {0.f, 0.f, 0.f, 0.f};
#pragma unroll
        for (int ct = 0; ct < 8; ct++) {
            int n = ct * 16 + l15;
            float bv = bupd[n];
#pragma unroll
            for (int r = 0; r < 4; r++) {
                float v = tokr[(size_t)(rsub + r) * ND + n] + fmaxf(accm[ct][r] + bv, 0.f);
                accm[ct][r] = v;
                s[r] += v;
                sq[r] += v * v;
            }
        }
        // Phase E: 16-lane reduce, normalize, write
#pragma unroll
        for (int ofs = 1; ofs < 16; ofs <<= 1) {
#pragma unroll
            for (int r = 0; r < 4; r++) {
                s[r]  += __shfl_xor(s[r], ofs, 64);
                sq[r] += __shfl_xor(sq[r], ofs, 64);
            }
        }
        float mu[4], rstd[4];
#pragma unroll
        for (int r = 0; r < 4; r++) {
            mu[r] = s[r] * (1.f / 128.f);
            rstd[r] = rsqrtf(sq[r] * (1.f / 128.f) - mu[r] * mu[r] + 1e-5f);
        }
#pragma unroll
        for (int ct = 0; ct < 8; ct++) {
            int n = ct * 16 + l15;
            float gn = g[n], bn = beta[n];
#pragma unroll
            for (int r = 0; r < 4; r++)
                out[(rbase + rsub + r) * ND + n] = (accm[ct][r] - mu[r]) * rstd[r] * gn + bn;
        }
    }
}

// ---------------------------------------------------------------------------
extern "C" void kernel_launch(void* const* d_in, const int* in_sizes, int n_in,
                              void* d_out, int out_size, void* d_ws, size_t ws_size,
                              hipStream_t stream) {
    const float* tok  = (const float*)d_in[0];
    const float* obj  = (const float*)d_in[1];
    const float* attn = (const float*)d_in[2];
    const float* Wmo  = (const float*)d_in[3];
    const float* bmo  = (const float*)d_in[4];
    const float* Wmt  = (const float*)d_in[5];
    const float* bmt  = (const float*)d_in[6];
    const float* Wut  = (const float*)d_in[7];
    const float* but  = (const float*)d_in[8];
    const float* Wuo  = (const float*)d_in[9];
    const float* buo  = (const float*)d_in[10];
    const float* gt   = (const float*)d_in[11];
    const float* bt   = (const float*)d_in[12];
    const float* go   = (const float*)d_in[13];
    const float* bo   = (const float*)d_in[14];
    float* out = (float*)d_out;

    u16* ws = (u16*)d_ws;
    u16* attnT  = ws;                        // 8388608 u16
    u16* tokT   = attnT + 8388608;           // 8388608
    u16* msg_oT = tokT + 8388608;            // 1048576 (swizzled)
    u16* WmoT   = msg_oT + 1048576;          // 16384
    u16* WmtT   = WmoT + 16384;              // 16384
    u16* WutT   = WmtT + 16384;              // 32768 (swizzled)
    u16* WuoT   = WutT + 32768;              // 32768
    u16* Psl    = WuoT + 32768;              // 4194304 (bf16 P slices [4][64][128][128])
    float* rs_part = (float*)(Psl + 4194304);// 32768 f32 = 65536 u16
    u16* attnB  = Psl + 4194304 + 65536;     // 8388608

    k_transpose<<<dim3(16384), dim3(256), 0, stream>>>(attn, tok, attnT, attnB, tokT);
    k_prep_weights<<<dim3(384), dim3(256), 0, stream>>>(Wmo, Wmt, Wut, Wuo, WmoT, WmtT, WutT, WuoT);
    k_msg_o<<<dim3(128), dim3(256), 0, stream>>>(obj, WmoT, bmo, msg_oT);
    k_obj_P<<<dim3(256), dim3(512), 0, stream>>>(attnT, tokT, Psl, rs_part);
    k_token_update<<<dim3(256), dim3(512), 0, stream>>>(tok, attnB, msg_oT, WutT, but, gt, bt, out);
    k_obj_final<<<dim3(256), dim3(256), 0, stream>>>(obj, Psl, rs_part, WmtT, bmt, WuoT, buo, go, bo,
                                                     out + (size_t)NB * NT * ND);
}

// Round 7
// 65.403 us; speedup vs baseline: 2.1626x; 1.3092x over previous
//
#include <hip/hip_runtime.h>

typedef unsigned short u16;
typedef __attribute__((ext_vector_type(8))) short bf16x8;
typedef __attribute__((ext_vector_type(4))) float f32x4;

#define NB 64
#define NT 1024
#define NO 128
#define ND 128

__device__ __forceinline__ u16 f2bf(float f) {
    union { float f; unsigned u; } v; v.f = f;
    unsigned r = v.u + 0x7FFFu + ((v.u >> 16) & 1u);
    return (u16)(r >> 16);
}
__device__ __forceinline__ float bf2f(short s) {
    union { unsigned u; float f; } v; v.u = ((unsigned)(u16)s) << 16; return v.f;
}

// load 8 consecutive fp32 and convert to a bf16x8 MFMA fragment
__device__ __forceinline__ bf16x8 frag_from_f32(const float* p) {
    const float4 a = *reinterpret_cast<const float4*>(p);
    const float4 b = *reinterpret_cast<const float4*>(p + 4);
    bf16x8 r;
    r[0] = (short)f2bf(a.x); r[1] = (short)f2bf(a.y);
    r[2] = (short)f2bf(a.z); r[3] = (short)f2bf(a.w);
    r[4] = (short)f2bf(b.x); r[5] = (short)f2bf(b.y);
    r[6] = (short)f2bf(b.z); r[7] = (short)f2bf(b.w);
    return r;
}

// ---------------------------------------------------------------------------
// Transpose+cast weights: W[k][n] fp32 -> WT[n][k] bf16.
// WutT is stored XOR-SWIZZLED (k ^= (n&7)<<3) for bank-conflict-free ds_read.
__global__ void k_prep_weights(const float* __restrict__ Wmo, const float* __restrict__ Wmt,
                               const float* __restrict__ Wut, const float* __restrict__ Wuo,
                               u16* __restrict__ WmoT, u16* __restrict__ WmtT,
                               u16* __restrict__ WutT, u16* __restrict__ WuoT) {
    int idx = blockIdx.x * 256 + threadIdx.x;
    if (idx < 16384) {
        int k = idx >> 7, n = idx & 127;
        WmoT[n * 128 + k] = f2bf(Wmo[idx]);
    } else if (idx < 32768) {
        int i = idx - 16384; int k = i >> 7, n = i & 127;
        WmtT[n * 128 + k] = f2bf(Wmt[i]);
    } else if (idx < 65536) {
        int i = idx - 32768; int k = i >> 7, n = i & 127;   // Wut is [256][128]
        WutT[n * 256 + (k ^ ((n & 7) << 3))] = f2bf(Wut[i]);   // swizzled
    } else if (idx < 98304) {
        int i = idx - 65536; int k = i >> 7, n = i & 127;
        WuoT[n * 256 + k] = f2bf(Wuo[i]);
    }
}

// ---------------------------------------------------------------------------
// msg_oT[b][n][o] = (obj[b] @ Wmo + bmo)^T, stored XOR-SWIZZLED in o within each n-row.
__global__ __launch_bounds__(256, 4)
void k_msg_o(const float* __restrict__ obj, const u16* __restrict__ WmoT,
             const float* __restrict__ bmo, u16* __restrict__ msg_oT) {
    __shared__ u16 lds_m[128][72];   // [n][row_local]
    int bid = blockIdx.x;
    int rows_base = bid * 64;
    int l = threadIdx.x & 63, w = threadIdx.x >> 6;
    int l15 = l & 15, lk = (l >> 4) * 8, rsub = (l >> 4) * 4;
    int wrow = w * 16;
    int row0 = rows_base + wrow;

    f32x4 acc[8] = {};
    const float* xp = obj + (size_t)(row0 + l15) * 128;
#pragma unroll
    for (int kk = 0; kk < 4; kk++) {
        bf16x8 a = frag_from_f32(xp + kk * 32 + lk);
#pragma unroll
        for (int ct = 0; ct < 8; ct++) {
            bf16x8 bfr = *reinterpret_cast<const bf16x8*>(WmoT + (ct * 16 + l15) * 128 + kk * 32 + lk);
            acc[ct] = __builtin_amdgcn_mfma_f32_16x16x32_bf16(a, bfr, acc[ct], 0, 0, 0);
        }
    }
#pragma unroll
    for (int ct = 0; ct < 8; ct++) {
        int n = ct * 16 + l15;
        float bv = bmo[n];
        ushort4 pk;
        pk.x = f2bf(acc[ct][0] + bv);
        pk.y = f2bf(acc[ct][1] + bv);
        pk.z = f2bf(acc[ct][2] + bv);
        pk.w = f2bf(acc[ct][3] + bv);
        *reinterpret_cast<ushort4*>(&lds_m[n][wrow + rsub]) = pk;
    }
    __syncthreads();
    int n = threadIdx.x >> 1, h = threadIdx.x & 1;
    const u16* src = &lds_m[n][h * 32];
    int b = rows_base >> 7, o0 = rows_base & 127;
    u16* rowp = msg_oT + (size_t)(b * 128 + n) * 128;
#pragma unroll
    for (int i = 0; i < 4; i++) {
        int off = o0 + h * 32 + i * 8;
        *reinterpret_cast<bf16x8*>(rowp + (off ^ ((n & 7) << 3))) =
            *reinterpret_cast<const bf16x8*>(src + i * 8);
    }
}

// ---------------------------------------------------------------------------
// Fused transpose + P-slice: P[b][o][d] (t-slice ks) = attn^T @ tok, plus rowsum(attn).
// Stages fp32 attn/tok slices into LDS transposed+swizzled (no HBM transpose buffers).
// grid = NB*4, 512 threads. LDS 128 KB -> 1 block/CU.
__global__ __launch_bounds__(512, 2)
void k_P(const float* __restrict__ attn, const float* __restrict__ tok,
         u16* __restrict__ Psl, float* __restrict__ rs_part) {
    __shared__ u16 aT[128 * 256];   // [o][t'] swizzled, 64 KB
    __shared__ u16 dT[128 * 256];   // [d][t'] swizzled, 64 KB
    int b = blockIdx.x >> 2, ks = blockIdx.x & 3;
    int kb = ks * 256;
    int tid = threadIdx.x;

    // ---- stage both slices: fp32 [256 t][128 c] -> LDS bf16 [c][t'] ----
    int og = (tid & 31) * 4;        // 4 consecutive c-rows per thread
    int tg = tid >> 5;              // 0..15 -> 16 t-rows each
    const float* asrc = attn + ((size_t)b * NT + kb) * 128;
    const float* tsrc = tok  + ((size_t)b * NT + kb) * 128;
#pragma unroll
    for (int half = 0; half < 2; half++) {
        const float* src = half ? tsrc : asrc;
        u16* buf = half ? dT : aT;
#pragma unroll
        for (int c = 0; c < 2; c++) {
            int t0 = tg * 16 + c * 8;
            f32x4 v[8];
#pragma unroll
            for (int i = 0; i < 8; i++)
                v[i] = *reinterpret_cast<const f32x4*>(src + (size_t)(t0 + i) * 128 + og);
            int gr = t0 >> 3;
#pragma unroll
            for (int j = 0; j < 4; j++) {
                int o = og + j;
                bf16x8 pk;
#pragma unroll
                for (int i = 0; i < 8; i++) pk[i] = (short)f2bf(v[i][j]);
                *reinterpret_cast<bf16x8*>(&buf[o * 256 + ((gr ^ (o & 31)) << 3)]) = pk;
            }
        }
    }
    __syncthreads();

    // ---- MFMA: P[o][d], K = 256 from LDS ----
    int l = tid & 63, w = tid >> 6;   // 8 waves: o-rows w*16..+15
    int l15 = l & 15, lk = (l >> 4) * 8, rsub = (l >> 4) * 4;
    int ro = w * 16 + l15;
    f32x4 acc[8] = {};
    float rsum = 0.f;
#pragma unroll
    for (int kk = 0; kk < 8; kk++) {
        int tt = kk * 32 + lk;
        bf16x8 a = *reinterpret_cast<const bf16x8*>(&aT[ro * 256 + (((tt >> 3) ^ (ro & 31)) << 3)]);
#pragma unroll
        for (int i = 0; i < 8; i++) rsum += bf2f(a[i]);
#pragma unroll
        for (int ct = 0; ct < 8; ct++) {
            int d = ct * 16 + l15;
            bf16x8 bf = *reinterpret_cast<const bf16x8*>(&dT[d * 256 + (((tt >> 3) ^ (d & 31)) << 3)]);
            acc[ct] = __builtin_amdgcn_mfma_f32_16x16x32_bf16(a, bf, acc[ct], 0, 0, 0);
        }
    }
    rsum += __shfl_xor(rsum, 16, 64);
    rsum += __shfl_xor(rsum, 32, 64);
    if (l < 16) rs_part[((size_t)ks * NB + b) * NO + w * 16 + l15] = rsum;
    u16* pout = Psl + (((size_t)(ks * NB + b)) * NO + w * 16) * ND;
#pragma unroll
    for (int ct = 0; ct < 8; ct++)
#pragma unroll
        for (int r = 0; r < 4; r++)
            pout[(size_t)(rsub + r) * ND + ct * 16 + l15] = f2bf(acc[ct][r]);
}

// ---------------------------------------------------------------------------
// Obj finalize: P = sum slices; agg = P@Wmt + rowsum*bmt; new_o = LN(obj + relu([obj,agg]@Wuo + buo))
__global__ __launch_bounds__(256, 4)
void k_obj_final(const float* __restrict__ obj, const u16* __restrict__ Psl,
                 const float* __restrict__ rs_part, const u16* __restrict__ WmtT,
                 const float* __restrict__ bmt, const u16* __restrict__ WuoT,
                 const float* __restrict__ buo, const float* __restrict__ g,
                 const float* __restrict__ beta, float* __restrict__ out) {
    __shared__ u16 P_lds[32][136];
    __shared__ u16 agg_lds[32][136];
    __shared__ float rs_lds[32];
    __shared__ float part_s[32][2], part_sq[32][2];
    int bid = blockIdx.x;
    int b = bid >> 2, ot = bid & 3;
    int ob = ot * 32;
    int tid = threadIdx.x;
    {   // slice-sum -> P_lds (bf16), rowsum -> rs_lds
        int row = tid >> 3, c0 = (tid & 7) * 16;
        float sm[16];
#pragma unroll
        for (int i = 0; i < 16; i++) sm[i] = 0.f;
#pragma unroll
        for (int ks = 0; ks < 4; ks++) {
            const u16* p = Psl + (((size_t)(ks * NB + b)) * NO + ob + row) * ND + c0;
            bf16x8 v0 = *reinterpret_cast<const bf16x8*>(p);
            bf16x8 v1 = *reinterpret_cast<const bf16x8*>(p + 8);
#pragma unroll
            for (int i = 0; i < 8; i++) { sm[i] += bf2f(v0[i]); sm[8 + i] += bf2f(v1[i]); }
        }
#pragma unroll
        for (int j = 0; j < 4; j++) {
            ushort4 pk;
            pk.x = f2bf(sm[j * 4 + 0]); pk.y = f2bf(sm[j * 4 + 1]);
            pk.z = f2bf(sm[j * 4 + 2]); pk.w = f2bf(sm[j * 4 + 3]);
            *reinterpret_cast<ushort4*>(&P_lds[row][c0 + j * 4]) = pk;
        }
        if (tid < 32) {
            float r = 0.f;
#pragma unroll
            for (int ks = 0; ks < 4; ks++) r += rs_part[((size_t)ks * NB + b) * NO + ob + tid];
            rs_lds[tid] = r;
        }
    }
    __syncthreads();
    int l = tid & 63, w = tid >> 6;
    int l15 = l & 15, lk = (l >> 4) * 8, rsub = (l >> 4) * 4;
    int wr = (w & 1) * 16, wc = (w >> 1) * 64;
    // agg = P @ Wmt (K=128) + rowsum*bmt
    f32x4 agg[4] = {};
#pragma unroll
    for (int kk = 0; kk < 4; kk++) {
        bf16x8 a = *reinterpret_cast<const bf16x8*>(&P_lds[wr + l15][kk * 32 + lk]);
#pragma unroll
        for (int ct = 0; ct < 4; ct++) {
            bf16x8 bf = *reinterpret_cast<const bf16x8*>(WmtT + (wc + ct * 16 + l15) * 128 + kk * 32 + lk);
            agg[ct] = __builtin_amdgcn_mfma_f32_16x16x32_bf16(a, bf, agg[ct], 0, 0, 0);
        }
    }
#pragma unroll
    for (int ct = 0; ct < 4; ct++) {
        int n = wc + ct * 16 + l15;
        float bb = bmt[n];
#pragma unroll
        for (int r = 0; r < 4; r++) {
            float v = agg[ct][r] + rs_lds[wr + rsub + r] * bb;
            agg_lds[wr + rsub + r][n] = f2bf(v);
        }
    }
    __syncthreads();
    // MLP K=256: [obj, agg] @ WuoT
    f32x4 accm[4] = {};
    const float* objp = obj + ((size_t)(b * NO) + ob + wr + l15) * ND;
#pragma unroll
    for (int kk = 0; kk < 8; kk++) {
        int k0 = kk * 32;
        bf16x8 a = (k0 < 128) ? frag_from_f32(objp + k0 + lk)
                              : *reinterpret_cast<const bf16x8*>(&agg_lds[wr + l15][k0 - 128 + lk]);
#pragma unroll
        for (int ct = 0; ct < 4; ct++) {
            bf16x8 bf = *reinterpret_cast<const bf16x8*>(WuoT + (wc + ct * 16 + l15) * 256 + k0 + lk);
            accm[ct] = __builtin_amdgcn_mfma_f32_16x16x32_bf16(a, bf, accm[ct], 0, 0, 0);
        }
    }
    // residual + relu + LN partials (64 cols per wave)
    const float* objr = obj + ((size_t)(b * NO) + ob) * ND;
    float s[4] = {0.f, 0.f, 0.f, 0.f}, sq[4] = {0.f, 0.f, 0.f, 0.f};
#pragma unroll
    for (int ct = 0; ct < 4; ct++) {
        int n = wc + ct * 16 + l15;
        float bv = buo[n];
#pragma unroll
        for (int r = 0; r < 4; r++) {
            int lr = wr + rsub + r;
            float v = objr[(size_t)lr * ND + n] + fmaxf(accm[ct][r] + bv, 0.f);
            accm[ct][r] = v;
            s[r] += v;
            sq[r] += v * v;
        }
    }
#pragma unroll
    for (int ofs = 1; ofs < 16; ofs <<= 1) {
#pragma unroll
        for (int r = 0; r < 4; r++) {
            s[r]  += __shfl_xor(s[r], ofs, 64);
            sq[r] += __shfl_xor(sq[r], ofs, 64);
        }
    }
    if (l15 < 4) {
        float sv = (l15 == 0) ? s[0] : (l15 == 1) ? s[1] : (l15 == 2) ? s[2] : s[3];
        float qv = (l15 == 0) ? sq[0] : (l15 == 1) ? sq[1] : (l15 == 2) ? sq[2] : sq[3];
        part_s[wr + rsub + l15][w >> 1] = sv;
        part_sq[wr + rsub + l15][w >> 1] = qv;
    }
    __syncthreads();
    float mu[4], rstd[4];
#pragma unroll
    for (int r = 0; r < 4; r++) {
        int lr = wr + rsub + r;
        float st = part_s[lr][0] + part_s[lr][1];
        float qt = part_sq[lr][0] + part_sq[lr][1];
        mu[r] = st * (1.f / 128.f);
        rstd[r] = rsqrtf(qt * (1.f / 128.f) - mu[r] * mu[r] + 1e-5f);
    }
#pragma unroll
    for (int ct = 0; ct < 4; ct++) {
        int n = wc + ct * 16 + l15;
        float gn = g[n], bn = beta[n];
#pragma unroll
        for (int r = 0; r < 4; r++) {
            int lr = wr + rsub + r;
            out[((size_t)(b * NO) + ob + lr) * ND + n] = (accm[ct][r] - mu[r]) * rstd[r] * gn + bn;
        }
    }
}

// ---------------------------------------------------------------------------
// Token side, LDS-panel structure: grid 256 (= 64 b x 4 quarter-batches), 512 thr.
// Stage msg_oT[b] (32KB) + WutT (64KB) into LDS once; each of 8 waves then does
// two independent 16-row x 128-col tiles (no barriers after staging).
// attn read directly as fp32 (converted in-flight).
__global__ __launch_bounds__(512, 2)
void k_token_update(const float* __restrict__ tok, const float* __restrict__ attn,
                    const u16* __restrict__ msg_oT, const u16* __restrict__ WutT,
                    const float* __restrict__ bupd, const float* __restrict__ g,
                    const float* __restrict__ beta, float* __restrict__ out) {
    __shared__ u16 msg_lds[16384];      // 32 KB, swizzled layout
    __shared__ u16 wut_lds[32768];      // 64 KB, swizzled layout
    __shared__ u16 agg_b[8][16][136];   // per-wave agg bounce, 34 KB
    int b = blockIdx.x >> 2, bq = blockIdx.x & 3;
    int tid = threadIdx.x;
    {   // stage panels (linear copy; swizzle already baked into global layout)
        const u16* msrc = msg_oT + (size_t)b * 16384;
#pragma unroll
        for (int i = 0; i < 4; i++) {
            int idx = (i * 512 + tid) * 8;
            *reinterpret_cast<bf16x8*>(&msg_lds[idx]) = *reinterpret_cast<const bf16x8*>(msrc + idx);
        }
#pragma unroll
        for (int i = 0; i < 8; i++) {
            int idx = (i * 512 + tid) * 8;
            *reinterpret_cast<bf16x8*>(&wut_lds[idx]) = *reinterpret_cast<const bf16x8*>(WutT + idx);
        }
    }
    __syncthreads();
    int l = tid & 63, w = tid >> 6;   // 8 waves
    int l15 = l & 15, lk = (l >> 4) * 8, rsub = (l >> 4) * 4;

#pragma unroll
    for (int pass = 0; pass < 2; pass++) {
        int trow = bq * 256 + pass * 128 + w * 16;
        size_t rbase = (size_t)b * NT + trow;

        // Phase A: agg = attn @ msg_o (K=128). A from global fp32, B from LDS.
        const float* aF = attn + (rbase + l15) * NO;
        bf16x8 af[4];
#pragma unroll
        for (int kk = 0; kk < 4; kk++)
            af[kk] = frag_from_f32(aF + kk * 32 + lk);
        f32x4 acc[8] = {};
#pragma unroll
        for (int kk = 0; kk < 4; kk++) {
#pragma unroll
            for (int ct = 0; ct < 8; ct++) {
                int n = ct * 16 + l15;
                bf16x8 bf = *reinterpret_cast<const bf16x8*>(
                    &msg_lds[n * 128 + ((kk * 32 + lk) ^ ((n & 7) << 3))]);
                acc[ct] = __builtin_amdgcn_mfma_f32_16x16x32_bf16(af[kk], bf, acc[ct], 0, 0, 0);
            }
        }
        // Phase B: acc -> wave-local agg bounce (C layout -> A layout)
#pragma unroll
        for (int ct = 0; ct < 8; ct++) {
            int n = ct * 16 + l15;
#pragma unroll
            for (int r = 0; r < 4; r++)
                agg_b[w][rsub + r][n] = f2bf(acc[ct][r]);
        }
        asm volatile("s_waitcnt lgkmcnt(0)" ::: "memory");
        __builtin_amdgcn_sched_barrier(0);
        // Phase C: MLP K=256. A: tok (global) + agg (LDS); B: wut_lds.
        const float* tokp = tok + (rbase + l15) * ND;
        bf16x8 am[8];
#pragma unroll
        for (int kk = 0; kk < 4; kk++)
            am[kk] = frag_from_f32(tokp + kk * 32 + lk);
#pragma unroll
        for (int kk = 0; kk < 4; kk++)
            am[4 + kk] = *reinterpret_cast<const bf16x8*>(&agg_b[w][l15][kk * 32 + lk]);
        f32x4 accm[8] = {};
#pragma unroll
        for (int kk = 0; kk < 8; kk++) {
#pragma unroll
            for (int ct = 0; ct < 8; ct++) {
                int n = ct * 16 + l15;
                bf16x8 bf = *reinterpret_cast<const bf16x8*>(
                    &wut_lds[n * 256 + ((kk * 32 + lk) ^ ((n & 7) << 3))]);
                accm[ct] = __builtin_amdgcn_mfma_f32_16x16x32_bf16(am[kk], bf, accm[ct], 0, 0, 0);
            }
        }
        // Phase D: residual + bias + relu + per-row partial sums (16 rows, wave-local)
        const float* tokr = tok + rbase * ND;
        float s[4] = {0.f, 0.f, 0.f, 0.f}, sq[4] = {0.f, 0.f, 0.f, 0.f};
#pragma unroll
        for (int ct = 0; ct < 8; ct++) {
            int n = ct * 16 + l15;
            float bv = bupd[n];
#pragma unroll
            for (int r = 0; r < 4; r++) {
                float v = tokr[(size_t)(rsub + r) * ND + n] + fmaxf(accm[ct][r] + bv, 0.f);
                accm[ct][r] = v;
                s[r] += v;
                sq[r] += v * v;
            }
        }
        // Phase E: 16-lane reduce, normalize, write
#pragma unroll
        for (int ofs = 1; ofs < 16; ofs <<= 1) {
#pragma unroll
            for (int r = 0; r < 4; r++) {
                s[r]  += __shfl_xor(s[r], ofs, 64);
                sq[r] += __shfl_xor(sq[r], ofs, 64);
            }
        }
        float mu[4], rstd[4];
#pragma unroll
        for (int r = 0; r < 4; r++) {
            mu[r] = s[r] * (1.f / 128.f);
            rstd[r] = rsqrtf(sq[r] * (1.f / 128.f) - mu[r] * mu[r] + 1e-5f);
        }
#pragma unroll
        for (int ct = 0; ct < 8; ct++) {
            int n = ct * 16 + l15;
            float gn = g[n], bn = beta[n];
#pragma unroll
            for (int r = 0; r < 4; r++)
                out[(rbase + rsub + r) * ND + n] = (accm[ct][r] - mu[r]) * rstd[r] * gn + bn;
        }
    }
}

// ---------------------------------------------------------------------------
extern "C" void kernel_launch(void* const* d_in, const int* in_sizes, int n_in,
                              void* d_out, int out_size, void* d_ws, size_t ws_size,
                              hipStream_t stream) {
    const float* tok  = (const float*)d_in[0];
    const float* obj  = (const float*)d_in[1];
    const float* attn = (const float*)d_in[2];
    const float* Wmo  = (const float*)d_in[3];
    const float* bmo  = (const float*)d_in[4];
    const float* Wmt  = (const float*)d_in[5];
    const float* bmt  = (const float*)d_in[6];
    const float* Wut  = (const float*)d_in[7];
    const float* but  = (const float*)d_in[8];
    const float* Wuo  = (const float*)d_in[9];
    const float* buo  = (const float*)d_in[10];
    const float* gt   = (const float*)d_in[11];
    const float* bt   = (const float*)d_in[12];
    const float* go   = (const float*)d_in[13];
    const float* bo   = (const float*)d_in[14];
    float* out = (float*)d_out;

    u16* ws = (u16*)d_ws;
    u16* msg_oT = ws;                        // 1048576 u16 (swizzled)
    u16* WmoT   = msg_oT + 1048576;          // 16384
    u16* WmtT   = WmoT + 16384;              // 16384
    u16* WutT   = WmtT + 16384;              // 32768 (swizzled)
    u16* WuoT   = WutT + 32768;              // 32768
    u16* Psl    = WuoT + 32768;              // 4194304 (bf16 P slices [4][64][128][128])
    float* rs_part = (float*)(Psl + 4194304);// 32768 f32

    k_prep_weights<<<dim3(384), dim3(256), 0, stream>>>(Wmo, Wmt, Wut, Wuo, WmoT, WmtT, WutT, WuoT);
    k_msg_o<<<dim3(128), dim3(256), 0, stream>>>(obj, WmoT, bmo, msg_oT);
    k_P<<<dim3(256), dim3(512), 0, stream>>>(attn, tok, Psl, rs_part);
    k_token_update<<<dim3(256), dim3(512), 0, stream>>>(tok, attn, msg_oT, WutT, but, gt, bt, out);
    k_obj_final<<<dim3(256), dim3(256), 0, stream>>>(obj, Psl, rs_part, WmtT, bmt, WuoT, buo, go, bo,
                                                     out + (size_t)NB * NT * ND);
}

// Round 8
// 61.437 us; speedup vs baseline: 2.3022x; 1.0646x over previous
//
#include <hip/hip_runtime.h>

typedef unsigned short u16;
typedef __attribute__((ext_vector_type(8))) short bf16x8;
typedef __attribute__((ext_vector_type(4))) float f32x4;

#define NB 64
#define NT 1024
#define NO 128
#define ND 128

__device__ __forceinline__ u16 f2bf(float f) {
    union { float f; unsigned u; } v; v.f = f;
    unsigned r = v.u + 0x7FFFu + ((v.u >> 16) & 1u);
    return (u16)(r >> 16);
}
__device__ __forceinline__ float bf2f(short s) {
    union { unsigned u; float f; } v; v.u = ((unsigned)(u16)s) << 16; return v.f;
}

// load 8 consecutive fp32 and convert to a bf16x8 MFMA fragment
__device__ __forceinline__ bf16x8 frag_from_f32(const float* p) {
    const float4 a = *reinterpret_cast<const float4*>(p);
    const float4 b = *reinterpret_cast<const float4*>(p + 4);
    bf16x8 r;
    r[0] = (short)f2bf(a.x); r[1] = (short)f2bf(a.y);
    r[2] = (short)f2bf(a.z); r[3] = (short)f2bf(a.w);
    r[4] = (short)f2bf(b.x); r[5] = (short)f2bf(b.y);
    r[6] = (short)f2bf(b.z); r[7] = (short)f2bf(b.w);
    return r;
}

// ---------------------------------------------------------------------------
// msg_oT[b][n][o] = (obj[b] @ Wmo + bmo)^T, stored XOR-SWIZZLED in o within each n-row.
// Self-contained: transposes Wmo via LDS. Also preps WmtT/WutT/WuoT (spread over blocks;
// consumers launch later on the same stream).
__global__ __launch_bounds__(256, 4)
void k_msg_o(const float* __restrict__ obj, const float* __restrict__ Wmo,
             const float* __restrict__ bmo,
             const float* __restrict__ Wmt, const float* __restrict__ Wut,
             const float* __restrict__ Wuo,
             u16* __restrict__ msg_oT, u16* __restrict__ WmtT,
             u16* __restrict__ WutT, u16* __restrict__ WuoT) {
    __shared__ u16 wT[128][136];     // Wmo^T bf16
    __shared__ u16 lds_m[128][72];   // output restage [n][row_local]
    int bid = blockIdx.x;
    int tid = threadIdx.x;

    // prep share of the other weight arrays (16384 + 32768 + 32768 = 81920 elems)
    for (int idx = bid * 256 + tid; idx < 81920; idx += 32768) {
        if (idx < 16384) {
            int k = idx >> 7, n = idx & 127;
            WmtT[n * 128 + k] = f2bf(Wmt[idx]);
        } else if (idx < 49152) {
            int i2 = idx - 16384; int k = i2 >> 7, n = i2 & 127;   // Wut [256][128]
            WutT[n * 256 + (k ^ ((n & 7) << 3))] = f2bf(Wut[i2]);  // swizzled
        } else {
            int i2 = idx - 49152; int k = i2 >> 7, n = i2 & 127;
            WuoT[n * 256 + k] = f2bf(Wuo[i2]);
        }
    }
    // transpose Wmo fp32 [k][n] -> wT[n][k] bf16
#pragma unroll
    for (int i = 0; i < 64; i++) {
        int idx = i * 256 + tid;
        int k = idx >> 7, n = idx & 127;
        wT[n][k] = f2bf(Wmo[idx]);
    }
    __syncthreads();

    int rows_base = bid * 64;
    int l = tid & 63, w = tid >> 6;
    int l15 = l & 15, lk = (l >> 4) * 8, rsub = (l >> 4) * 4;
    int wrow = w * 16;
    int row0 = rows_base + wrow;

    f32x4 acc[8] = {};
    const float* xp = obj + (size_t)(row0 + l15) * 128;
#pragma unroll
    for (int kk = 0; kk < 4; kk++) {
        bf16x8 a = frag_from_f32(xp + kk * 32 + lk);
#pragma unroll
        for (int ct = 0; ct < 8; ct++) {
            bf16x8 bfr = *reinterpret_cast<const bf16x8*>(&wT[ct * 16 + l15][kk * 32 + lk]);
            acc[ct] = __builtin_amdgcn_mfma_f32_16x16x32_bf16(a, bfr, acc[ct], 0, 0, 0);
        }
    }
#pragma unroll
    for (int ct = 0; ct < 8; ct++) {
        int n = ct * 16 + l15;
        float bv = bmo[n];
        ushort4 pk;
        pk.x = f2bf(acc[ct][0] + bv);
        pk.y = f2bf(acc[ct][1] + bv);
        pk.z = f2bf(acc[ct][2] + bv);
        pk.w = f2bf(acc[ct][3] + bv);
        *reinterpret_cast<ushort4*>(&lds_m[n][wrow + rsub]) = pk;
    }
    __syncthreads();
    int n = tid >> 1, h = tid & 1;
    const u16* src = &lds_m[n][h * 32];
    int b = rows_base >> 7, o0 = rows_base & 127;
    u16* rowp = msg_oT + (size_t)(b * 128 + n) * 128;
#pragma unroll
    for (int i = 0; i < 4; i++) {
        int off = o0 + h * 32 + i * 8;
        *reinterpret_cast<bf16x8*>(rowp + (off ^ ((n & 7) << 3))) =
            *reinterpret_cast<const bf16x8*>(src + i * 8);
    }
}

// ---------------------------------------------------------------------------
// Fused transpose + P-slice: P[b][o][d] (t-slice ks) = attn^T @ tok + rowsum(attn).
// 64 KB LDS (two 128-t chunks per slice) -> 2 blocks/CU for stage/MFMA overlap.
__global__ __launch_bounds__(512, 4)
void k_P(const float* __restrict__ attn, const float* __restrict__ tok,
         u16* __restrict__ Psl, float* __restrict__ rs_part) {
    __shared__ u16 aT[128 * 128];   // [o][t'] swizzled, 32 KB
    __shared__ u16 dT[128 * 128];   // [d][t'] swizzled, 32 KB
    int b = blockIdx.x >> 2, ks = blockIdx.x & 3;
    int tid = threadIdx.x;
    int l = tid & 63, w = tid >> 6;   // 8 waves: o-rows w*16..+15
    int l15 = l & 15, lk = (l >> 4) * 8, rsub = (l >> 4) * 4;
    int ro = w * 16 + l15;
    int og = (tid & 31) * 4;        // 4 consecutive c-rows per thread
    int tg = tid >> 5;              // 0..15 -> 8 t-rows each

    f32x4 acc[8] = {};
    float rsum = 0.f;
#pragma unroll
    for (int c = 0; c < 2; c++) {
        int kb = ks * 256 + c * 128;
        const float* asrc = attn + ((size_t)b * NT + kb) * 128;
        const float* tsrc = tok  + ((size_t)b * NT + kb) * 128;
        if (c) __syncthreads();   // prior chunk's MFMA reads done before overwrite
        // ---- stage: fp32 [128 t][128 c] -> LDS bf16 [c][t'] swizzled ----
#pragma unroll
        for (int half = 0; half < 2; half++) {
            const float* src = half ? tsrc : asrc;
            u16* buf = half ? dT : aT;
            int t0 = tg * 8;
            f32x4 v[8];
#pragma unroll
            for (int i = 0; i < 8; i++)
                v[i] = *reinterpret_cast<const f32x4*>(src + (size_t)(t0 + i) * 128 + og);
            int gr = t0 >> 3;   // 0..15
#pragma unroll
            for (int j = 0; j < 4; j++) {
                int o = og + j;
                bf16x8 pk;
#pragma unroll
                for (int i = 0; i < 8; i++) pk[i] = (short)f2bf(v[i][j]);
                *reinterpret_cast<bf16x8*>(&buf[o * 128 + ((gr ^ (o & 15)) << 3)]) = pk;
            }
        }
        __syncthreads();
        // ---- MFMA: K = 128 for this chunk ----
#pragma unroll
        for (int kk = 0; kk < 4; kk++) {
            int tt = kk * 32 + lk;
            bf16x8 a = *reinterpret_cast<const bf16x8*>(
                &aT[ro * 128 + (((tt >> 3) ^ (ro & 15)) << 3)]);
#pragma unroll
            for (int i = 0; i < 8; i++) rsum += bf2f(a[i]);
#pragma unroll
            for (int ct = 0; ct < 8; ct++) {
                int d = ct * 16 + l15;
                bf16x8 bf = *reinterpret_cast<const bf16x8*>(
                    &dT[d * 128 + (((tt >> 3) ^ (d & 15)) << 3)]);
                acc[ct] = __builtin_amdgcn_mfma_f32_16x16x32_bf16(a, bf, acc[ct], 0, 0, 0);
            }
        }
    }
    rsum += __shfl_xor(rsum, 16, 64);
    rsum += __shfl_xor(rsum, 32, 64);
    if (l < 16) rs_part[((size_t)ks * NB + b) * NO + w * 16 + l15] = rsum;
    u16* pout = Psl + (((size_t)(ks * NB + b)) * NO + w * 16) * ND;
#pragma unroll
    for (int ct = 0; ct < 8; ct++)
#pragma unroll
        for (int r = 0; r < 4; r++)
            pout[(size_t)(rsub + r) * ND + ct * 16 + l15] = f2bf(acc[ct][r]);
}

// ---------------------------------------------------------------------------
// Obj finalize: P = sum slices; agg = P@Wmt + rowsum*bmt; new_o = LN(obj + relu([obj,agg]@Wuo + buo))
__global__ __launch_bounds__(256, 4)
void k_obj_final(const float* __restrict__ obj, const u16* __restrict__ Psl,
                 const float* __restrict__ rs_part, const u16* __restrict__ WmtT,
                 const float* __restrict__ bmt, const u16* __restrict__ WuoT,
                 const float* __restrict__ buo, const float* __restrict__ g,
                 const float* __restrict__ beta, float* __restrict__ out) {
    __shared__ u16 P_lds[32][136];
    __shared__ u16 agg_lds[32][136];
    __shared__ float rs_lds[32];
    __shared__ float part_s[32][2], part_sq[32][2];
    int bid = blockIdx.x;
    int b = bid >> 2, ot = bid & 3;
    int ob = ot * 32;
    int tid = threadIdx.x;
    {   // slice-sum -> P_lds (bf16), rowsum -> rs_lds
        int row = tid >> 3, c0 = (tid & 7) * 16;
        float sm[16];
#pragma unroll
        for (int i = 0; i < 16; i++) sm[i] = 0.f;
#pragma unroll
        for (int ks = 0; ks < 4; ks++) {
            const u16* p = Psl + (((size_t)(ks * NB + b)) * NO + ob + row) * ND + c0;
            bf16x8 v0 = *reinterpret_cast<const bf16x8*>(p);
            bf16x8 v1 = *reinterpret_cast<const bf16x8*>(p + 8);
#pragma unroll
            for (int i = 0; i < 8; i++) { sm[i] += bf2f(v0[i]); sm[8 + i] += bf2f(v1[i]); }
        }
#pragma unroll
        for (int j = 0; j < 4; j++) {
            ushort4 pk;
            pk.x = f2bf(sm[j * 4 + 0]); pk.y = f2bf(sm[j * 4 + 1]);
            pk.z = f2bf(sm[j * 4 + 2]); pk.w = f2bf(sm[j * 4 + 3]);
            *reinterpret_cast<ushort4*>(&P_lds[row][c0 + j * 4]) = pk;
        }
        if (tid < 32) {
            float r = 0.f;
#pragma unroll
            for (int ks = 0; ks < 4; ks++) r += rs_part[((size_t)ks * NB + b) * NO + ob + tid];
            rs_lds[tid] = r;
        }
    }
    __syncthreads();
    int l = tid & 63, w = tid >> 6;
    int l15 = l & 15, lk = (l >> 4) * 8, rsub = (l >> 4) * 4;
    int wr = (w & 1) * 16, wc = (w >> 1) * 64;
    // agg = P @ Wmt (K=128) + rowsum*bmt
    f32x4 agg[4] = {};
#pragma unroll
    for (int kk = 0; kk < 4; kk++) {
        bf16x8 a = *reinterpret_cast<const bf16x8*>(&P_lds[wr + l15][kk * 32 + lk]);
#pragma unroll
        for (int ct = 0; ct < 4; ct++) {
            bf16x8 bf = *reinterpret_cast<const bf16x8*>(WmtT + (wc + ct * 16 + l15) * 128 + kk * 32 + lk);
            agg[ct] = __builtin_amdgcn_mfma_f32_16x16x32_bf16(a, bf, agg[ct], 0, 0, 0);
        }
    }
#pragma unroll
    for (int ct = 0; ct < 4; ct++) {
        int n = wc + ct * 16 + l15;
        float bb = bmt[n];
#pragma unroll
        for (int r = 0; r < 4; r++) {
            float v = agg[ct][r] + rs_lds[wr + rsub + r] * bb;
            agg_lds[wr + rsub + r][n] = f2bf(v);
        }
    }
    __syncthreads();
    // MLP K=256: [obj, agg] @ WuoT
    f32x4 accm[4] = {};
    const float* objp = obj + ((size_t)(b * NO) + ob + wr + l15) * ND;
#pragma unroll
    for (int kk = 0; kk < 8; kk++) {
        int k0 = kk * 32;
        bf16x8 a = (k0 < 128) ? frag_from_f32(objp + k0 + lk)
                              : *reinterpret_cast<const bf16x8*>(&agg_lds[wr + l15][k0 - 128 + lk]);
#pragma unroll
        for (int ct = 0; ct < 4; ct++) {
            bf16x8 bf = *reinterpret_cast<const bf16x8*>(WuoT + (wc + ct * 16 + l15) * 256 + k0 + lk);
            accm[ct] = __builtin_amdgcn_mfma_f32_16x16x32_bf16(a, bf, accm[ct], 0, 0, 0);
        }
    }
    // residual + relu + LN partials (64 cols per wave)
    const float* objr = obj + ((size_t)(b * NO) + ob) * ND;
    float s[4] = {0.f, 0.f, 0.f, 0.f}, sq[4] = {0.f, 0.f, 0.f, 0.f};
#pragma unroll
    for (int ct = 0; ct < 4; ct++) {
        int n = wc + ct * 16 + l15;
        float bv = buo[n];
#pragma unroll
        for (int r = 0; r < 4; r++) {
            int lr = wr + rsub + r;
            float v = objr[(size_t)lr * ND + n] + fmaxf(accm[ct][r] + bv, 0.f);
            accm[ct][r] = v;
            s[r] += v;
            sq[r] += v * v;
        }
    }
#pragma unroll
    for (int ofs = 1; ofs < 16; ofs <<= 1) {
#pragma unroll
        for (int r = 0; r < 4; r++) {
            s[r]  += __shfl_xor(s[r], ofs, 64);
            sq[r] += __shfl_xor(sq[r], ofs, 64);
        }
    }
    if (l15 < 4) {
        float sv = (l15 == 0) ? s[0] : (l15 == 1) ? s[1] : (l15 == 2) ? s[2] : s[3];
        float qv = (l15 == 0) ? sq[0] : (l15 == 1) ? sq[1] : (l15 == 2) ? sq[2] : sq[3];
        part_s[wr + rsub + l15][w >> 1] = sv;
        part_sq[wr + rsub + l15][w >> 1] = qv;
    }
    __syncthreads();
    float mu[4], rstd[4];
#pragma unroll
    for (int r = 0; r < 4; r++) {
        int lr = wr + rsub + r;
        float st = part_s[lr][0] + part_s[lr][1];
        float qt = part_sq[lr][0] + part_sq[lr][1];
        mu[r] = st * (1.f / 128.f);
        rstd[r] = rsqrtf(qt * (1.f / 128.f) - mu[r] * mu[r] + 1e-5f);
    }
#pragma unroll
    for (int ct = 0; ct < 4; ct++) {
        int n = wc + ct * 16 + l15;
        float gn = g[n], bn = beta[n];
#pragma unroll
        for (int r = 0; r < 4; r++) {
            int lr = wr + rsub + r;
            out[((size_t)(b * NO) + ob + lr) * ND + n] = (accm[ct][r] - mu[r]) * rstd[r] * gn + bn;
        }
    }
}

// ---------------------------------------------------------------------------
// Token side, LDS-panel structure: grid 256 (= 64 b x 4 quarter-batches), 512 thr.
// Stage msg_oT[b] (32KB) + WutT (64KB) into LDS once; each of 8 waves then does
// two independent 16-row x 128-col tiles (no barriers after staging).
__global__ __launch_bounds__(512, 2)
void k_token_update(const float* __restrict__ tok, const float* __restrict__ attn,
                    const u16* __restrict__ msg_oT, const u16* __restrict__ WutT,
                    const float* __restrict__ bupd, const float* __restrict__ g,
                    const float* __restrict__ beta, float* __restrict__ out) {
    __shared__ u16 msg_lds[16384];      // 32 KB, swizzled layout
    __shared__ u16 wut_lds[32768];      // 64 KB, swizzled layout
    __shared__ u16 agg_b[8][16][136];   // per-wave agg bounce, 34 KB
    int b = blockIdx.x >> 2, bq = blockIdx.x & 3;
    int tid = threadIdx.x;
    {   // stage panels (linear copy; swizzle already baked into global layout)
        const u16* msrc = msg_oT + (size_t)b * 16384;
#pragma unroll
        for (int i = 0; i < 4; i++) {
            int idx = (i * 512 + tid) * 8;
            *reinterpret_cast<bf16x8*>(&msg_lds[idx]) = *reinterpret_cast<const bf16x8*>(msrc + idx);
        }
#pragma unroll
        for (int i = 0; i < 8; i++) {
            int idx = (i * 512 + tid) * 8;
            *reinterpret_cast<bf16x8*>(&wut_lds[idx]) = *reinterpret_cast<const bf16x8*>(WutT + idx);
        }
    }
    __syncthreads();
    int l = tid & 63, w = tid >> 6;   // 8 waves
    int l15 = l & 15, lk = (l >> 4) * 8, rsub = (l >> 4) * 4;

#pragma unroll
    for (int pass = 0; pass < 2; pass++) {
        int trow = bq * 256 + pass * 128 + w * 16;
        size_t rbase = (size_t)b * NT + trow;

        // Phase A: agg = attn @ msg_o (K=128). A from global fp32, B from LDS.
        const float* aF = attn + (rbase + l15) * NO;
        bf16x8 af[4];
#pragma unroll
        for (int kk = 0; kk < 4; kk++)
            af[kk] = frag_from_f32(aF + kk * 32 + lk);
        f32x4 acc[8] = {};
#pragma unroll
        for (int kk = 0; kk < 4; kk++) {
#pragma unroll
            for (int ct = 0; ct < 8; ct++) {
                int n = ct * 16 + l15;
                bf16x8 bf = *reinterpret_cast<const bf16x8*>(
                    &msg_lds[n * 128 + ((kk * 32 + lk) ^ ((n & 7) << 3))]);
                acc[ct] = __builtin_amdgcn_mfma_f32_16x16x32_bf16(af[kk], bf, acc[ct], 0, 0, 0);
            }
        }
        // Phase B: acc -> wave-local agg bounce (C layout -> A layout)
#pragma unroll
        for (int ct = 0; ct < 8; ct++) {
            int n = ct * 16 + l15;
#pragma unroll
            for (int r = 0; r < 4; r++)
                agg_b[w][rsub + r][n] = f2bf(acc[ct][r]);
        }
        asm volatile("s_waitcnt lgkmcnt(0)" ::: "memory");
        __builtin_amdgcn_sched_barrier(0);
        // Phase C: MLP K=256. A: tok (global) + agg (LDS); B: wut_lds.
        const float* tokp = tok + (rbase + l15) * ND;
        bf16x8 am[8];
#pragma unroll
        for (int kk = 0; kk < 4; kk++)
            am[kk] = frag_from_f32(tokp + kk * 32 + lk);
#pragma unroll
        for (int kk = 0; kk < 4; kk++)
            am[4 + kk] = *reinterpret_cast<const bf16x8*>(&agg_b[w][l15][kk * 32 + lk]);
        f32x4 accm[8] = {};
#pragma unroll
        for (int kk = 0; kk < 8; kk++) {
#pragma unroll
            for (int ct = 0; ct < 8; ct++) {
                int n = ct * 16 + l15;
                bf16x8 bf = *reinterpret_cast<const bf16x8*>(
                    &wut_lds[n * 256 + ((kk * 32 + lk) ^ ((n & 7) << 3))]);
                accm[ct] = __builtin_amdgcn_mfma_f32_16x16x32_bf16(am[kk], bf, accm[ct], 0, 0, 0);
            }
        }
        // Phase D: residual + bias + relu + per-row partial sums (16 rows, wave-local)
        const float* tokr = tok + rbase * ND;
        float s[4] = {0.f, 0.f, 0.f, 0.f}, sq[4] = {0.f, 0.f, 0.f, 0.f};
#pragma unroll
        for (int ct = 0; ct < 8; ct++) {
            int n = ct * 16 + l15;
            float bv = bupd[n];
#pragma unroll
            for (int r = 0; r < 4; r++) {
                float v = tokr[(size_t)(rsub + r) * ND + n] + fmaxf(accm[ct][r] + bv, 0.f);
                accm[ct][r] = v;
                s[r] += v;
                sq[r] += v * v;
            }
        }
        // Phase E: 16-lane reduce, normalize, write
#pragma unroll
        for (int ofs = 1; ofs < 16; ofs <<= 1) {
#pragma unroll
            for (int r = 0; r < 4; r++) {
                s[r]  += __shfl_xor(s[r], ofs, 64);
                sq[r] += __shfl_xor(sq[r], ofs, 64);
            }
        }
        float mu[4], rstd[4];
#pragma unroll
        for (int r = 0; r < 4; r++) {
            mu[r] = s[r] * (1.f / 128.f);
            rstd[r] = rsqrtf(sq[r] * (1.f / 128.f) - mu[r] * mu[r] + 1e-5f);
        }
#pragma unroll
        for (int ct = 0; ct < 8; ct++) {
            int n = ct * 16 + l15;
            float gn = g[n], bn = beta[n];
#pragma unroll
            for (int r = 0; r < 4; r++)
                out[(rbase + rsub + r) * ND + n] = (accm[ct][r] - mu[r]) * rstd[r] * gn + bn;
        }
    }
}

// ---------------------------------------------------------------------------
extern "C" void kernel_launch(void* const* d_in, const int* in_sizes, int n_in,
                              void* d_out, int out_size, void* d_ws, size_t ws_size,
                              hipStream_t stream) {
    const float* tok  = (const float*)d_in[0];
    const float* obj  = (const float*)d_in[1];
    const float* attn = (const float*)d_in[2];
    const float* Wmo  = (const float*)d_in[3];
    const float* bmo  = (const float*)d_in[4];
    const float* Wmt  = (const float*)d_in[5];
    const float* bmt  = (const float*)d_in[6];
    const float* Wut  = (const float*)d_in[7];
    const float* but  = (const float*)d_in[8];
    const float* Wuo  = (const float*)d_in[9];
    const float* buo  = (const float*)d_in[10];
    const float* gt   = (const float*)d_in[11];
    const float* bt   = (const float*)d_in[12];
    const float* go   = (const float*)d_in[13];
    const float* bo   = (const float*)d_in[14];
    float* out = (float*)d_out;

    u16* ws = (u16*)d_ws;
    u16* msg_oT = ws;                        // 1048576 u16 (swizzled)
    u16* WmtT   = msg_oT + 1048576;          // 16384
    u16* WutT   = WmtT + 16384;              // 32768 (swizzled)
    u16* WuoT   = WutT + 32768;              // 32768
    u16* Psl    = WuoT + 32768;              // 4194304 (bf16 P slices [4][64][128][128])
    float* rs_part = (float*)(Psl + 4194304);// 32768 f32

    k_msg_o<<<dim3(128), dim3(256), 0, stream>>>(obj, Wmo, bmo, Wmt, Wut, Wuo,
                                                 msg_oT, WmtT, WutT, WuoT);
    k_P<<<dim3(256), dim3(512), 0, stream>>>(attn, tok, Psl, rs_part);
    k_token_update<<<dim3(256), dim3(512), 0, stream>>>(tok, attn, msg_oT, WutT, but, gt, bt, out);
    k_obj_final<<<dim3(256), dim3(256), 0, stream>>>(obj, Psl, rs_part, WmtT, bmt, WuoT, buo, go, bo,
                                                     out + (size_t)NB * NT * ND);
}

// Round 9
// 55.778 us; speedup vs baseline: 2.5358x; 1.1014x over previous
//
#include <hip/hip_runtime.h>

typedef unsigned short u16;
typedef __attribute__((ext_vector_type(8))) short bf16x8;
typedef __attribute__((ext_vector_type(4))) float f32x4;

#define NB 64
#define NT 1024
#define NO 128
#define ND 128

__device__ __forceinline__ u16 f2bf(float f) {
    union { float f; unsigned u; } v; v.f = f;
    unsigned r = v.u + 0x7FFFu + ((v.u >> 16) & 1u);
    return (u16)(r >> 16);
}
__device__ __forceinline__ float bf2f(short s) {
    union { unsigned u; float f; } v; v.u = ((unsigned)(u16)s) << 16; return v.f;
}

// load 8 consecutive fp32 and convert to a bf16x8 MFMA fragment
__device__ __forceinline__ bf16x8 frag_from_f32(const float* p) {
    const float4 a = *reinterpret_cast<const float4*>(p);
    const float4 b = *reinterpret_cast<const float4*>(p + 4);
    bf16x8 r;
    r[0] = (short)f2bf(a.x); r[1] = (short)f2bf(a.y);
    r[2] = (short)f2bf(a.z); r[3] = (short)f2bf(a.w);
    r[4] = (short)f2bf(b.x); r[5] = (short)f2bf(b.y);
    r[6] = (short)f2bf(b.z); r[7] = (short)f2bf(b.w);
    return r;
}

// ---------------------------------------------------------------------------
// k_P: fused transpose + P-slice GEMM  (P[b] = attn[b]^T @ tok[b], split-K over 4 slices)
//      + weight prep (spread over all blocks)
//      + msg_oT[b] = (obj[b]@Wmo + bmo)^T computed as a tail on ks==0 blocks.
// 64 KB LDS -> 2 blocks/CU.
__global__ __launch_bounds__(512, 4)
void k_P(const float* __restrict__ attn, const float* __restrict__ tok,
         const float* __restrict__ obj, const float* __restrict__ Wmo,
         const float* __restrict__ bmo, const float* __restrict__ Wmt,
         const float* __restrict__ Wut, const float* __restrict__ Wuo,
         u16* __restrict__ Psl, float* __restrict__ rs_part,
         u16* __restrict__ msg_oT, u16* __restrict__ WmtT,
         u16* __restrict__ WutT, u16* __restrict__ WuoT) {
    __shared__ u16 aT[128 * 128];   // [o][t'] swizzled, 32 KB
    __shared__ u16 dT[128 * 128];   // [d][t'] swizzled, 32 KB
    int b = blockIdx.x >> 2, ks = blockIdx.x & 3;
    int tid = threadIdx.x;

    // ---- weight prep: one element per thread across the grid ----
    {
        int idx = blockIdx.x * 512 + tid;
        if (idx < 16384) {
            int k = idx >> 7, n = idx & 127;
            WmtT[n * 128 + k] = f2bf(Wmt[idx]);
        } else if (idx < 49152) {
            int i2 = idx - 16384; int k = i2 >> 7, n = i2 & 127;   // Wut [256][128]
            WutT[n * 256 + (k ^ ((n & 7) << 3))] = f2bf(Wut[i2]);  // swizzled
        } else if (idx < 81920) {
            int i2 = idx - 49152; int k = i2 >> 7, n = i2 & 127;
            WuoT[n * 256 + k] = f2bf(Wuo[i2]);
        }
    }

    int l = tid & 63, w = tid >> 6;   // 8 waves: o-rows w*16..+15
    int l15 = l & 15, lk = (l >> 4) * 8, rsub = (l >> 4) * 4;
    int ro = w * 16 + l15;
    int og = (tid & 31) * 4;        // 4 consecutive c-rows per thread
    int tg = tid >> 5;              // 0..15 -> 8 t-rows each

    f32x4 acc[8] = {};
    float rsum = 0.f;
#pragma unroll
    for (int c = 0; c < 2; c++) {
        int kb = ks * 256 + c * 128;
        const float* asrc = attn + ((size_t)b * NT + kb) * 128;
        const float* tsrc = tok  + ((size_t)b * NT + kb) * 128;
        if (c) __syncthreads();   // prior chunk's MFMA reads done before overwrite
        // ---- stage: fp32 [128 t][128 c] -> LDS bf16 [c][t'] swizzled ----
#pragma unroll
        for (int half = 0; half < 2; half++) {
            const float* src = half ? tsrc : asrc;
            u16* buf = half ? dT : aT;
            int t0 = tg * 8;
            f32x4 v[8];
#pragma unroll
            for (int i = 0; i < 8; i++)
                v[i] = *reinterpret_cast<const f32x4*>(src + (size_t)(t0 + i) * 128 + og);
            int gr = t0 >> 3;   // 0..15
#pragma unroll
            for (int j = 0; j < 4; j++) {
                int o = og + j;
                bf16x8 pk;
#pragma unroll
                for (int i = 0; i < 8; i++) pk[i] = (short)f2bf(v[i][j]);
                *reinterpret_cast<bf16x8*>(&buf[o * 128 + ((gr ^ (o & 15)) << 3)]) = pk;
            }
        }
        __syncthreads();
        // ---- MFMA: K = 128 for this chunk ----
#pragma unroll
        for (int kk = 0; kk < 4; kk++) {
            int tt = kk * 32 + lk;
            bf16x8 a = *reinterpret_cast<const bf16x8*>(
                &aT[ro * 128 + (((tt >> 3) ^ (ro & 15)) << 3)]);
#pragma unroll
            for (int i = 0; i < 8; i++) rsum += bf2f(a[i]);
#pragma unroll
            for (int ct = 0; ct < 8; ct++) {
                int d = ct * 16 + l15;
                bf16x8 bf = *reinterpret_cast<const bf16x8*>(
                    &dT[d * 128 + (((tt >> 3) ^ (d & 15)) << 3)]);
                acc[ct] = __builtin_amdgcn_mfma_f32_16x16x32_bf16(a, bf, acc[ct], 0, 0, 0);
            }
        }
    }
    rsum += __shfl_xor(rsum, 16, 64);
    rsum += __shfl_xor(rsum, 32, 64);
    if (l < 16) rs_part[((size_t)ks * NB + b) * NO + w * 16 + l15] = rsum;
    u16* pout = Psl + (((size_t)(ks * NB + b)) * NO + w * 16) * ND;
#pragma unroll
    for (int ct = 0; ct < 8; ct++)
#pragma unroll
        for (int r = 0; r < 4; r++)
            pout[(size_t)(rsub + r) * ND + ct * 16 + l15] = f2bf(acc[ct][r]);

    // ---- msg_o tail: only ks==0 blocks; reuse aT (WmoT) and dT (output restage) ----
    if (ks == 0) {
        __syncthreads();
        // stage Wmo^T bf16, XOR-swizzled, into aT
#pragma unroll
        for (int i = 0; i < 32; i++) {
            int idx = i * 512 + tid;
            int k = idx >> 7, n = idx & 127;
            aT[n * 128 + (k ^ ((n & 7) << 3))] = f2bf(Wmo[idx]);
        }
        __syncthreads();
        // msg = obj[b] @ Wmo + bmo  (rows o = w*16..+15, cols n = 0..127)
        f32x4 mc[8] = {};
        const float* xp = obj + ((size_t)b * NO + w * 16 + l15) * 128;
#pragma unroll
        for (int kk = 0; kk < 4; kk++) {
            bf16x8 a = frag_from_f32(xp + kk * 32 + lk);
#pragma unroll
            for (int ct = 0; ct < 8; ct++) {
                int n = ct * 16 + l15;
                bf16x8 bfr = *reinterpret_cast<const bf16x8*>(
                    &aT[n * 128 + ((kk * 32 + lk) ^ ((n & 7) << 3))]);
                mc[ct] = __builtin_amdgcn_mfma_f32_16x16x32_bf16(a, bfr, mc[ct], 0, 0, 0);
            }
        }
        // store swizzled into dT[n][o^swz]
#pragma unroll
        for (int ct = 0; ct < 8; ct++) {
            int n = ct * 16 + l15;
            float bv = bmo[n];
            ushort4 pk;
            pk.x = f2bf(mc[ct][0] + bv);
            pk.y = f2bf(mc[ct][1] + bv);
            pk.z = f2bf(mc[ct][2] + bv);
            pk.w = f2bf(mc[ct][3] + bv);
            int o = w * 16 + rsub;
            *reinterpret_cast<ushort4*>(&dT[n * 128 + (o ^ ((n & 7) << 3))]) = pk;
        }
        __syncthreads();
        // linear coalesced copy dT -> msg_oT[b] (layout preserved, stays swizzled)
        u16* mout = msg_oT + (size_t)b * 16384;
#pragma unroll
        for (int i = 0; i < 4; i++) {
            int idx2 = (i * 512 + tid) * 8;
            *reinterpret_cast<bf16x8*>(mout + idx2) = *reinterpret_cast<const bf16x8*>(&dT[idx2]);
        }
    }
}

// ---------------------------------------------------------------------------
// Obj finalize: P = sum slices; agg = P@Wmt + rowsum*bmt; new_o = LN(obj + relu([obj,agg]@Wuo + buo))
__global__ __launch_bounds__(256, 4)
void k_obj_final(const float* __restrict__ obj, const u16* __restrict__ Psl,
                 const float* __restrict__ rs_part, const u16* __restrict__ WmtT,
                 const float* __restrict__ bmt, const u16* __restrict__ WuoT,
                 const float* __restrict__ buo, const float* __restrict__ g,
                 const float* __restrict__ beta, float* __restrict__ out) {
    __shared__ u16 P_lds[32][136];
    __shared__ u16 agg_lds[32][136];
    __shared__ float rs_lds[32];
    __shared__ float part_s[32][2], part_sq[32][2];
    int bid = blockIdx.x;
    int b = bid >> 2, ot = bid & 3;
    int ob = ot * 32;
    int tid = threadIdx.x;
    {   // slice-sum -> P_lds (bf16), rowsum -> rs_lds
        int row = tid >> 3, c0 = (tid & 7) * 16;
        float sm[16];
#pragma unroll
        for (int i = 0; i < 16; i++) sm[i] = 0.f;
#pragma unroll
        for (int ks = 0; ks < 4; ks++) {
            const u16* p = Psl + (((size_t)(ks * NB + b)) * NO + ob + row) * ND + c0;
            bf16x8 v0 = *reinterpret_cast<const bf16x8*>(p);
            bf16x8 v1 = *reinterpret_cast<const bf16x8*>(p + 8);
#pragma unroll
            for (int i = 0; i < 8; i++) { sm[i] += bf2f(v0[i]); sm[8 + i] += bf2f(v1[i]); }
        }
#pragma unroll
        for (int j = 0; j < 4; j++) {
            ushort4 pk;
            pk.x = f2bf(sm[j * 4 + 0]); pk.y = f2bf(sm[j * 4 + 1]);
            pk.z = f2bf(sm[j * 4 + 2]); pk.w = f2bf(sm[j * 4 + 3]);
            *reinterpret_cast<ushort4*>(&P_lds[row][c0 + j * 4]) = pk;
        }
        if (tid < 32) {
            float r = 0.f;
#pragma unroll
            for (int ks = 0; ks < 4; ks++) r += rs_part[((size_t)ks * NB + b) * NO + ob + tid];
            rs_lds[tid] = r;
        }
    }
    __syncthreads();
    int l = tid & 63, w = tid >> 6;
    int l15 = l & 15, lk = (l >> 4) * 8, rsub = (l >> 4) * 4;
    int wr = (w & 1) * 16, wc = (w >> 1) * 64;
    // agg = P @ Wmt (K=128) + rowsum*bmt
    f32x4 agg[4] = {};
#pragma unroll
    for (int kk = 0; kk < 4; kk++) {
        bf16x8 a = *reinterpret_cast<const bf16x8*>(&P_lds[wr + l15][kk * 32 + lk]);
#pragma unroll
        for (int ct = 0; ct < 4; ct++) {
            bf16x8 bf = *reinterpret_cast<const bf16x8*>(WmtT + (wc + ct * 16 + l15) * 128 + kk * 32 + lk);
            agg[ct] = __builtin_amdgcn_mfma_f32_16x16x32_bf16(a, bf, agg[ct], 0, 0, 0);
        }
    }
#pragma unroll
    for (int ct = 0; ct < 4; ct++) {
        int n = wc + ct * 16 + l15;
        float bb = bmt[n];
#pragma unroll
        for (int r = 0; r < 4; r++) {
            float v = agg[ct][r] + rs_lds[wr + rsub + r] * bb;
            agg_lds[wr + rsub + r][n] = f2bf(v);
        }
    }
    __syncthreads();
    // MLP K=256: [obj, agg] @ WuoT
    f32x4 accm[4] = {};
    const float* objp = obj + ((size_t)(b * NO) + ob + wr + l15) * ND;
#pragma unroll
    for (int kk = 0; kk < 8; kk++) {
        int k0 = kk * 32;
        bf16x8 a = (k0 < 128) ? frag_from_f32(objp + k0 + lk)
                              : *reinterpret_cast<const bf16x8*>(&agg_lds[wr + l15][k0 - 128 + lk]);
#pragma unroll
        for (int ct = 0; ct < 4; ct++) {
            bf16x8 bf = *reinterpret_cast<const bf16x8*>(WuoT + (wc + ct * 16 + l15) * 256 + k0 + lk);
            accm[ct] = __builtin_amdgcn_mfma_f32_16x16x32_bf16(a, bf, accm[ct], 0, 0, 0);
        }
    }
    // residual + relu + LN partials (64 cols per wave)
    const float* objr = obj + ((size_t)(b * NO) + ob) * ND;
    float s[4] = {0.f, 0.f, 0.f, 0.f}, sq[4] = {0.f, 0.f, 0.f, 0.f};
#pragma unroll
    for (int ct = 0; ct < 4; ct++) {
        int n = wc + ct * 16 + l15;
        float bv = buo[n];
#pragma unroll
        for (int r = 0; r < 4; r++) {
            int lr = wr + rsub + r;
            float v = objr[(size_t)lr * ND + n] + fmaxf(accm[ct][r] + bv, 0.f);
            accm[ct][r] = v;
            s[r] += v;
            sq[r] += v * v;
        }
    }
#pragma unroll
    for (int ofs = 1; ofs < 16; ofs <<= 1) {
#pragma unroll
        for (int r = 0; r < 4; r++) {
            s[r]  += __shfl_xor(s[r], ofs, 64);
            sq[r] += __shfl_xor(sq[r], ofs, 64);
        }
    }
    if (l15 < 4) {
        float sv = (l15 == 0) ? s[0] : (l15 == 1) ? s[1] : (l15 == 2) ? s[2] : s[3];
        float qv = (l15 == 0) ? sq[0] : (l15 == 1) ? sq[1] : (l15 == 2) ? sq[2] : sq[3];
        part_s[wr + rsub + l15][w >> 1] = sv;
        part_sq[wr + rsub + l15][w >> 1] = qv;
    }
    __syncthreads();
    float mu[4], rstd[4];
#pragma unroll
    for (int r = 0; r < 4; r++) {
        int lr = wr + rsub + r;
        float st = part_s[lr][0] + part_s[lr][1];
        float qt = part_sq[lr][0] + part_sq[lr][1];
        mu[r] = st * (1.f / 128.f);
        rstd[r] = rsqrtf(qt * (1.f / 128.f) - mu[r] * mu[r] + 1e-5f);
    }
#pragma unroll
    for (int ct = 0; ct < 4; ct++) {
        int n = wc + ct * 16 + l15;
        float gn = g[n], bn = beta[n];
#pragma unroll
        for (int r = 0; r < 4; r++) {
            int lr = wr + rsub + r;
            out[((size_t)(b * NO) + ob + lr) * ND + n] = (accm[ct][r] - mu[r]) * rstd[r] * gn + bn;
        }
    }
}

// ---------------------------------------------------------------------------
// Token side, LDS-panel structure: grid 256, 512 thr, XCD-swizzled block mapping
// (4 quarter-blocks of one batch land on the same XCD for msg/wut L2 reuse).
// All per-pass global loads hoisted to the pass top to maximize in-flight loads.
__global__ __launch_bounds__(512, 2)
void k_token_update(const float* __restrict__ tok, const float* __restrict__ attn,
                    const u16* __restrict__ msg_oT, const u16* __restrict__ WutT,
                    const float* __restrict__ bupd, const float* __restrict__ g,
                    const float* __restrict__ beta, float* __restrict__ out) {
    __shared__ u16 msg_lds[16384];      // 32 KB, swizzled layout
    __shared__ u16 wut_lds[32768];      // 64 KB, swizzled layout
    __shared__ u16 agg_b[8][16][136];   // per-wave agg bounce, 34 KB
    int i = blockIdx.x;
    int b  = ((i >> 5) << 3) + (i & 7);   // bijective XCD-grouping swizzle
    int bq = (i >> 3) & 3;
    int tid = threadIdx.x;
    {   // stage panels (linear copy; swizzle already baked into global layout)
        const u16* msrc = msg_oT + (size_t)b * 16384;
#pragma unroll
        for (int k = 0; k < 4; k++) {
            int idx = (k * 512 + tid) * 8;
            *reinterpret_cast<bf16x8*>(&msg_lds[idx]) = *reinterpret_cast<const bf16x8*>(msrc + idx);
        }
#pragma unroll
        for (int k = 0; k < 8; k++) {
            int idx = (k * 512 + tid) * 8;
            *reinterpret_cast<bf16x8*>(&wut_lds[idx]) = *reinterpret_cast<const bf16x8*>(WutT + idx);
        }
    }
    __syncthreads();
    int l = tid & 63, w = tid >> 6;   // 8 waves
    int l15 = l & 15, lk = (l >> 4) * 8, rsub = (l >> 4) * 4;

#pragma unroll
    for (int pass = 0; pass < 2; pass++) {
        int trow = bq * 256 + pass * 128 + w * 16;
        size_t rbase = (size_t)b * NT + trow;
        const float* aF   = attn + (rbase + l15) * NO;
        const float* tokp = tok + (rbase + l15) * ND;
        const float* tokr = tok + rbase * ND;

        // ---- hoisted global loads: attn frags, tok frags, residual ----
        bf16x8 af[4];
#pragma unroll
        for (int kk = 0; kk < 4; kk++)
            af[kk] = frag_from_f32(aF + kk * 32 + lk);
        bf16x8 am0[4];
#pragma unroll
        for (int kk = 0; kk < 4; kk++)
            am0[kk] = frag_from_f32(tokp + kk * 32 + lk);
        float resv[8][4];
#pragma unroll
        for (int ct = 0; ct < 8; ct++)
#pragma unroll
            for (int r = 0; r < 4; r++)
                resv[ct][r] = tokr[(size_t)(rsub + r) * ND + ct * 16 + l15];

        // Phase A: agg = attn @ msg_o (K=128), B from LDS.
        f32x4 acc[8] = {};
#pragma unroll
        for (int kk = 0; kk < 4; kk++) {
#pragma unroll
            for (int ct = 0; ct < 8; ct++) {
                int n = ct * 16 + l15;
                bf16x8 bf = *reinterpret_cast<const bf16x8*>(
                    &msg_lds[n * 128 + ((kk * 32 + lk) ^ ((n & 7) << 3))]);
                acc[ct] = __builtin_amdgcn_mfma_f32_16x16x32_bf16(af[kk], bf, acc[ct], 0, 0, 0);
            }
        }
        // Phase B: acc -> wave-local agg bounce (C layout -> A layout)
#pragma unroll
        for (int ct = 0; ct < 8; ct++) {
            int n = ct * 16 + l15;
#pragma unroll
            for (int r = 0; r < 4; r++)
                agg_b[w][rsub + r][n] = f2bf(acc[ct][r]);
        }
        asm volatile("s_waitcnt lgkmcnt(0)" ::: "memory");
        __builtin_amdgcn_sched_barrier(0);
        // Phase C: MLP K=256. A: tok frags (preloaded) + agg (LDS); B: wut_lds.
        bf16x8 am[8];
#pragma unroll
        for (int kk = 0; kk < 4; kk++) am[kk] = am0[kk];
#pragma unroll
        for (int kk = 0; kk < 4; kk++)
            am[4 + kk] = *reinterpret_cast<const bf16x8*>(&agg_b[w][l15][kk * 32 + lk]);
        f32x4 accm[8] = {};
#pragma unroll
        for (int kk = 0; kk < 8; kk++) {
#pragma unroll
            for (int ct = 0; ct < 8; ct++) {
                int n = ct * 16 + l15;
                bf16x8 bf = *reinterpret_cast<const bf16x8*>(
                    &wut_lds[n * 256 + ((kk * 32 + lk) ^ ((n & 7) << 3))]);
                accm[ct] = __builtin_amdgcn_mfma_f32_16x16x32_bf16(am[kk], bf, accm[ct], 0, 0, 0);
            }
        }
        // Phase D: residual + bias + relu + per-row partial sums (preloaded residual)
        float s[4] = {0.f, 0.f, 0.f, 0.f}, sq[4] = {0.f, 0.f, 0.f, 0.f};
#pragma unroll
        for (int ct = 0; ct < 8; ct++) {
            int n = ct * 16 + l15;
            float bv = bupd[n];
#pragma unroll
            for (int r = 0; r < 4; r++) {
                float v = resv[ct][r] + fmaxf(accm[ct][r] + bv, 0.f);
                accm[ct][r] = v;
                s[r] += v;
                sq[r] += v * v;
            }
        }
        // Phase E: 16-lane reduce, normalize, write
#pragma unroll
        for (int ofs = 1; ofs < 16; ofs <<= 1) {
#pragma unroll
            for (int r = 0; r < 4; r++) {
                s[r]  += __shfl_xor(s[r], ofs, 64);
                sq[r] += __shfl_xor(sq[r], ofs, 64);
            }
        }
        float mu[4], rstd[4];
#pragma unroll
        for (int r = 0; r < 4; r++) {
            mu[r] = s[r] * (1.f / 128.f);
            rstd[r] = rsqrtf(sq[r] * (1.f / 128.f) - mu[r] * mu[r] + 1e-5f);
        }
#pragma unroll
        for (int ct = 0; ct < 8; ct++) {
            int n = ct * 16 + l15;
            float gn = g[n], bn = beta[n];
#pragma unroll
            for (int r = 0; r < 4; r++)
                out[(rbase + rsub + r) * ND + n] = (accm[ct][r] - mu[r]) * rstd[r] * gn + bn;
        }
    }
}

// ---------------------------------------------------------------------------
extern "C" void kernel_launch(void* const* d_in, const int* in_sizes, int n_in,
                              void* d_out, int out_size, void* d_ws, size_t ws_size,
                              hipStream_t stream) {
    const float* tok  = (const float*)d_in[0];
    const float* obj  = (const float*)d_in[1];
    const float* attn = (const float*)d_in[2];
    const float* Wmo  = (const float*)d_in[3];
    const float* bmo  = (const float*)d_in[4];
    const float* Wmt  = (const float*)d_in[5];
    const float* bmt  = (const float*)d_in[6];
    const float* Wut  = (const float*)d_in[7];
    const float* but  = (const float*)d_in[8];
    const float* Wuo  = (const float*)d_in[9];
    const float* buo  = (const float*)d_in[10];
    const float* gt   = (const float*)d_in[11];
    const float* bt   = (const float*)d_in[12];
    const float* go   = (const float*)d_in[13];
    const float* bo   = (const float*)d_in[14];
    float* out = (float*)d_out;

    u16* ws = (u16*)d_ws;
    u16* msg_oT = ws;                        // 1048576 u16 (swizzled)
    u16* WmtT   = msg_oT + 1048576;          // 16384
    u16* WutT   = WmtT + 16384;              // 32768 (swizzled)
    u16* WuoT   = WutT + 32768;              // 32768
    u16* Psl    = WuoT + 32768;              // 4194304 (bf16 P slices [4][64][128][128])
    float* rs_part = (float*)(Psl + 4194304);// 32768 f32

    k_P<<<dim3(256), dim3(512), 0, stream>>>(attn, tok, obj, Wmo, bmo, Wmt, Wut, Wuo,
                                             Psl, rs_part, msg_oT, WmtT, WutT, WuoT);
    k_token_update<<<dim3(256), dim3(512), 0, stream>>>(tok, attn, msg_oT, WutT, but, gt, bt, out);
    k_obj_final<<<dim3(256), dim3(256), 0, stream>>>(obj, Psl, rs_part, WmtT, bmt, WuoT, buo, go, bo,
                                                     out + (size_t)NB * NT * ND);
}